// Round 17
// baseline (311.007 us; speedup 1.0000x reference)
//
#include <hip/hip_runtime.h>
#include <hip/hip_bf16.h>
#include <hip/hip_fp8.h>
#include <math.h>

#define B_ 8
#define N_ 512
#define K_ 16
#define D_ 256
#define F_ 1024
#define H_ 8
#define HD_ 32
#define M_ (B_*N_)      // 4096 rows (b,n)
#define R_ (B_*N_*K_)   // 65536 edge rows

typedef __bf16 bf16x8 __attribute__((ext_vector_type(8)));
typedef float  f32x4  __attribute__((ext_vector_type(4)));
typedef long   i64x2  __attribute__((ext_vector_type(2)));

__device__ inline short bf16s(float f) {
    __hip_bfloat16 h = __float2bfloat16(f);
    return *reinterpret_cast<short*>(&h);
}
__device__ inline float b2f(short s) {
    union { float f; unsigned u; } v; v.u = ((unsigned)(unsigned short)s) << 16; return v.f;
}
__device__ inline unsigned char f8e4m3(float f) {
    union { __hip_fp8_e4m3 h; unsigned char c; } u;
    u.h = __hip_fp8_e4m3(f);
    return u.c;
}
// exact GELU via Abramowitz-Stegun 7.1.26 erf (|eps| <= 1.5e-7): cheap VALU
__device__ __forceinline__ float gelu_f(float x) {
    const float z = fabsf(x) * 0.70710678118654752f;
    const float t = __builtin_amdgcn_rcpf(1.f + 0.3275911f*z);
    const float p = t*(0.254829592f + t*(-0.284496736f + t*(1.421413741f
                  + t*(-1.453152027f + t*1.061405429f))));
    float er = 1.f - p*__expf(-z*z);
    er = (x >= 0.f) ? er : -er;
    return 0.5f*x*(1.f + er);
}
// packed+swizzled fp8 position within a 64B k-chunk: slot q=(w&31)>>3 holds the
// two 8B k-groups {8q.., 32+8q..}; slot XOR'd by row&3. w = k&63.
__device__ __forceinline__ int f8pos(int w, int row) {
    return ((((w >> 3) & 3) ^ (row & 3)) << 4) | ((w >> 5) << 3) | (w & 7);
}
// hidden-dim relabeling (exact; applied to BOTH hid tensors and W2 rows):
// within each 64-chunk, w -> (w&15)*4 + ((w>>4)&3)  (16x4 transpose)
__device__ __forceinline__ int hperm(int k) {
    return (k & ~63) | ((k & 15) << 2) | ((k >> 4) & 3);
}
// bf16 slot swizzle for 64B-row LDS tiles (T2, producer side): within each
// 32-short row chunk, 8-short slot s -> s ^ (row&3). Applied to e2b and eW1T.
__device__ __forceinline__ int bslot(int k, int row) {   // k = short idx in row
    return (k & ~31) | ((((k >> 3) & 3) ^ (row & 3)) << 3) | (k & 7);
}

// async global->LDS, 16B per lane; lds base must be wave-uniform (dest = base + lane*16)
__device__ __forceinline__ void gload16(const void* g, void* l) {
    __builtin_amdgcn_global_load_lds(
        (const __attribute__((address_space(1))) unsigned int*)g,
        (__attribute__((address_space(3))) unsigned int*)l, 16, 0, 0);
}

// ---------------- all weight transposes in one launch (grid.z selects) ------
// z==5 (nW2): rows stored at hperm(k). z==6 (eW1): slot-swizzled (bslot).
// z==7 (eW2): fp8 e4m3 x64, packed+swizzled at k'=hperm(k).
__global__ __launch_bounds__(256) void transposeAll(
        const float* __restrict__ Wq, const float* __restrict__ Wk,
        const float* __restrict__ Wv, const float* __restrict__ Wo,
        const float* __restrict__ nW1, const float* __restrict__ nW2,
        const float* __restrict__ eW1, const float* __restrict__ eW2,
        short* __restrict__ WqkvT, short* __restrict__ WoT,
        short* __restrict__ nW1T, short* __restrict__ nW2T,
        short* __restrict__ eW1T, unsigned char* __restrict__ eW2T8)
{
    const float* W; short* WT = nullptr; int Kk, Nn; float sc = 1.f;
    switch (blockIdx.z) {
        case 0: W=Wq;  WT=WqkvT;          Kk=256;  Nn=256;  sc=0.17677669529663687f; break;
        case 1: W=Wk;  WT=WqkvT+256*256;  Kk=256;  Nn=256;  break;
        case 2: W=Wv;  WT=WqkvT+512*256;  Kk=256;  Nn=256;  break;
        case 3: W=Wo;  WT=WoT;            Kk=256;  Nn=256;  break;
        case 4: W=nW1; WT=nW1T;           Kk=256;  Nn=1024; break;
        case 5: W=nW2; WT=nW2T;           Kk=1024; Nn=256;  break;
        case 6: W=eW1; WT=eW1T;           Kk=256;  Nn=1024; break;
        default:W=eW2;                    Kk=1024; Nn=256;  break;
    }
    const int bx = blockIdx.x, by = blockIdx.y;
    if (bx >= Nn/32 || by >= Kk/32) return;
    __shared__ float tile[32][33];
    int tx = threadIdx.x & 31, ty = threadIdx.x >> 5;   // 32x8
    #pragma unroll
    for (int j = 0; j < 4; ++j) {
        int k = by*32 + ty + j*8;
        tile[ty + j*8][tx] = W[(size_t)k*Nn + bx*32 + tx];
    }
    __syncthreads();
    if (blockIdx.z == 7) {
        #pragma unroll
        for (int j = 0; j < 4; ++j) {
            int n = bx*32 + ty + j*8;
            int kp = hperm(by*32 + tx);
            eW2T8[(size_t)n*1024 + (kp & ~63) + f8pos(kp & 63, n)] =
                f8e4m3(tile[tx][ty + j*8] * 64.f);
        }
    } else if (blockIdx.z == 5) {
        #pragma unroll
        for (int j = 0; j < 4; ++j) {
            int n = bx*32 + ty + j*8;
            WT[(size_t)n*1024 + hperm(by*32 + tx)] = bf16s(tile[tx][ty + j*8]);
        }
    } else if (blockIdx.z == 6) {
        #pragma unroll
        for (int j = 0; j < 4; ++j) {
            int n = bx*32 + ty + j*8;
            WT[(size_t)n*Kk + bslot(by*32 + tx, n)] = bf16s(tile[tx][ty + j*8]);
        }
    } else {
        #pragma unroll
        for (int j = 0; j < 4; ++j) {
            int n = bx*32 + ty + j*8;
            WT[(size_t)n*Kk + by*32 + tx] = bf16s(tile[tx][ty + j*8] * sc);
        }
    }
}

__global__ __launch_bounds__(256) void build_bqkv(const float* __restrict__ bq,
        const float* __restrict__ bk, const float* __restrict__ bv,
        float* __restrict__ bqkv)
{
    int t = blockIdx.x*256 + threadIdx.x;
    if (t >= 768) return;
    float v = (t < 256) ? bq[t]*0.17677669529663687f
            : (t < 512) ? bk[t-256] : bv[t-512];
    bqkv[t] = v;
}

// ---------------- x (N,B,D) f32 -> xtb (B*N, D) bf16 ------------------------
__global__ __launch_bounds__(256) void conv_x(const float* __restrict__ x,
        short* __restrict__ xtb)
{
    int row = blockIdx.x;         // b*N+n
    int d = threadIdx.x;
    int b = row >> 9, n = row & 511;
    xtb[(size_t)row*D_ + d] = bf16s(x[((size_t)n*B_ + b)*D_ + d]);
}

// ---------------- means[b,i,k] = mean_d e ----------------------------------
__global__ __launch_bounds__(256) void edge_means(const float* __restrict__ e,
        float* __restrict__ means)
{
    long row = (long)blockIdx.x*4 + (threadIdx.x >> 6);
    int lane = threadIdx.x & 63;
    float4 v = ((const float4*)(e + row*D_))[lane];
    float s = v.x + v.y + v.z + v.w;
    for (int o = 1; o < 64; o <<= 1) s += __shfl_xor(s, o);
    if (lane == 0) means[row] = s * (1.f/D_);
}

// zero 16 rows + serial per-row scatter (numpy last-wins) in one kernel
__global__ __launch_bounds__(256) void bias_build(const int* __restrict__ ei,
        const float* __restrict__ means, float* __restrict__ biasb)
{
    const int r0 = blockIdx.x * 16;       // 16 (b,i) rows per block
    float4* bp4 = (float4*)(biasb + (size_t)r0*N_);
    #pragma unroll
    for (int i = threadIdx.x; i < 16*N_/4; i += 256)
        bp4[i] = make_float4(0.f, 0.f, 0.f, 0.f);
    __syncthreads();
    if (threadIdx.x < 16) {
        const int idx = r0 + threadIdx.x;
        const int* ep = ei + (size_t)idx*K_;
        const float* mp = means + (size_t)idx*K_;
        float* bp = biasb + (size_t)idx*N_;
        for (int k = 0; k < K_; ++k) bp[ep[k]] = mp[k];
    }
}

// ---------------- 128x128 bf16 MFMA GEMM: QKV split output ------------------
__global__ __launch_bounds__(256) void gemm_qkv(
        const short* __restrict__ A, const short* __restrict__ BT,
        const float* __restrict__ bias, short* __restrict__ Cb,
        short* __restrict__ vtb, int Kk)
{
    __shared__ __align__(16) short As[128*32];
    __shared__ __align__(16) short Bs[128*32];
    const int t = threadIdx.x;
    const int lane = t & 63;
    const int wave = t >> 6;
    const int wr = (wave >> 1) * 64;
    const int wc = (wave & 1) * 64;
    const int bm = blockIdx.x, bn = blockIdx.y;
    f32x4 acc[4][4] = {};
    const int srow = lane >> 2;       // staging row within 16-row group
    const int sk   = (lane & 3) * 8;  // staging k offset (8 bf16 = 16B)
    const int fr = lane & 15;
    const int fk = (lane >> 4) * 8;
    for (int k0 = 0; k0 < Kk; k0 += 32) {
        __syncthreads();
        #pragma unroll
        for (int i = 0; i < 2; ++i) {
            const int rb = wave*16 + i*64;
            gload16(A  + (size_t)(bm*128 + rb + srow)*Kk + k0 + sk, &As[rb*32]);
            gload16(BT + (size_t)(bn*128 + rb + srow)*Kk + k0 + sk, &Bs[rb*32]);
        }
        __syncthreads();
        bf16x8 af[4], bfr[4];
        #pragma unroll
        for (int i2 = 0; i2 < 4; ++i2)
            af[i2] = *(const bf16x8*)&As[(wr + i2*16 + fr)*32 + fk];
        #pragma unroll
        for (int n2 = 0; n2 < 4; ++n2)
            bfr[n2] = *(const bf16x8*)&Bs[(wc + n2*16 + fr)*32 + fk];
        #pragma unroll
        for (int i2 = 0; i2 < 4; ++i2)
            #pragma unroll
            for (int n2 = 0; n2 < 4; ++n2)
                acc[i2][n2] = __builtin_amdgcn_mfma_f32_16x16x32_bf16(
                        af[i2], bfr[n2], acc[i2][n2], 0, 0, 0);
    }
    const int fq4 = (lane >> 4) * 4;
    #pragma unroll
    for (int i2 = 0; i2 < 4; ++i2) {
        #pragma unroll
        for (int n2 = 0; n2 < 4; ++n2) {
            const int col = bn*128 + wc + n2*16 + fr;
            const float bv = bias[col];
            const int rowb = bm*128 + wr + i2*16 + fq4;
            if (col < 512) {
                #pragma unroll
                for (int r2 = 0; r2 < 4; ++r2)
                    Cb[(size_t)(rowb + r2)*512 + col] = bf16s(acc[i2][n2][r2] + bv);
            } else {
                const int b = rowb >> 9, n = rowb & 511;
                const int dv = col - 512, h = dv >> 5, dh = dv & 31;
                short4 s4;
                s4.x = bf16s(acc[i2][n2][0] + bv);
                s4.y = bf16s(acc[i2][n2][1] + bv);
                s4.z = bf16s(acc[i2][n2][2] + bv);
                s4.w = bf16s(acc[i2][n2][3] + bv);
                *(short4*)&vtb[((size_t)((b*H_ + h)*HD_ + dh))*512 + n] = s4;
            }
        }
    }
}

// -- 128x256 8-wave GEMM + GELU -> packed fp8 (edge W1) ----------------------
// 2-deep prefetch + counted vmcnt (T4). A (e2b) and B (eW1T) are slot-swizzled
// at the source (bslot) so fragment ds_read_b128 is ~4-way instead of 8-way.
__global__ __launch_bounds__(512, 4) void gemm_gelu_f8(
        const short* __restrict__ A, const short* __restrict__ BT,
        const float* __restrict__ bias, unsigned char* __restrict__ C8, int Kk)
{
    __shared__ __align__(16) short As[2][128*32];
    __shared__ __align__(16) short Bs[2][256*32];
    const int t = threadIdx.x;
    const int lane = t & 63;
    const int wave = t >> 6;
    const int wrg = (wave >> 2) * 64;     // row group 0/64
    const int wc  = (wave & 3) * 64;      // col group 0..192
    const int bm = blockIdx.x, bn = blockIdx.y;
    f32x4 acc[4][4] = {};
    const int srow = lane >> 2;
    const int sk   = (lane & 3) * 8;
    const int fr = lane & 15;
    const int fs = lane >> 4;             // fragment slot 0..3
    auto stage = [&](int s, int k0) {
        {
            const int rb = wave*16;   // A: 128 rows, 1 gload/wave
            gload16(A + (size_t)(bm*128 + rb + srow)*Kk + k0 + sk, &As[s][rb*32]);
        }
        #pragma unroll
        for (int i = 0; i < 2; ++i) {  // B: 256 rows, 2 gloads/wave
            const int rb = wave*16 + i*128;
            gload16(BT + (size_t)(bn*256 + rb + srow)*Kk + k0 + sk, &Bs[s][rb*32]);
        }
    };
    stage(0, 0);
    stage(1, 32);
    asm volatile("s_waitcnt vmcnt(3)" ::: "memory");   // own tile-0 loads landed
    __builtin_amdgcn_sched_barrier(0);
    __builtin_amdgcn_s_barrier();                      // all waves' tile-0 landed
    #pragma unroll
    for (int tt = 0; tt < 8; ++tt) {                   // Kk == 256, 8 tiles
        const int cur = tt & 1;
        bf16x8 af[4], bfr[4];
        #pragma unroll
        for (int i2 = 0; i2 < 4; ++i2) {
            const int row = wrg + i2*16 + fr;
            af[i2] = *(const bf16x8*)&As[cur][row*32 + ((fs ^ (row & 3)) << 3)];
        }
        #pragma unroll
        for (int n2 = 0; n2 < 4; ++n2) {
            const int row = wc + n2*16 + fr;
            bfr[n2] = *(const bf16x8*)&Bs[cur][row*32 + ((fs ^ (row & 3)) << 3)];
        }
        asm volatile("s_waitcnt lgkmcnt(0)" ::: "memory");  // own frags in regs
        __builtin_amdgcn_sched_barrier(0);
        __builtin_amdgcn_s_barrier();                  // all waves done reading cur
        if (tt + 2 < 8) stage(cur, (tt + 2) * 32);     // overwrite freed buffer
        #pragma unroll
        for (int i2 = 0; i2 < 4; ++i2)
            #pragma unroll
            for (int n2 = 0; n2 < 4; ++n2)
                acc[i2][n2] = __builtin_amdgcn_mfma_f32_16x16x32_bf16(
                        af[i2], bfr[n2], acc[i2][n2], 0, 0, 0);
        if (tt + 2 < 8) { asm volatile("s_waitcnt vmcnt(3)" ::: "memory"); }
        else            { asm volatile("s_waitcnt vmcnt(0)" ::: "memory"); }
        __builtin_amdgcn_sched_barrier(0);
        __builtin_amdgcn_s_barrier();                  // next tile ready for all
    }
    const int fq4 = (lane >> 4) * 4;
    const int chunk = (bn*4 + (wc >> 6)) * 64;   // this wave's 64-wide k'-chunk
    #pragma unroll
    for (int i2 = 0; i2 < 4; ++i2) {
        #pragma unroll
        for (int r2 = 0; r2 < 4; ++r2) {
            const int row = bm*128 + wrg + i2*16 + fq4 + r2;
            float v[4];
            #pragma unroll
            for (int n2 = 0; n2 < 4; ++n2)
                v[n2] = gelu_f(acc[i2][n2][r2] + bias[bn*256 + wc + n2*16 + fr]);
            int word = __builtin_amdgcn_cvt_pk_fp8_f32(v[0]*16.f, v[1]*16.f, 0, false);
            word = __builtin_amdgcn_cvt_pk_fp8_f32(v[2]*16.f, v[3]*16.f, word, true);
            *(unsigned int*)(C8 + (size_t)row*1024 + chunk + f8pos(fr*4, row))
                = (unsigned int)word;
        }
    }
}

// -- 64x256 4-wave GEMM, 2-phase prefetch dbuf (node path / Wo: grid >= 64) --
// MODE 0: + GELU -> bf16 hperm-packed out (node W1; grid (M/64, Nn/256))
// MODE 1: + bias + x-residual (N,B,D) + LN -> f32 out + bf16 outb (Wo)
// MODE 2: + bias + f32 residual + LN -> f32 out transposed (N,B,D) (node W2)
template<int MODE>
__global__ __launch_bounds__(256, 3) void gemm64(
        const short* __restrict__ A, const short* __restrict__ BT,
        const float* __restrict__ bias, const float* __restrict__ resf,
        const float* __restrict__ g, const float* __restrict__ bt,
        float* __restrict__ out, short* __restrict__ outb, int Kk)
{
    __shared__ __align__(16) short As[2][64*32];    // 4 KB x2
    __shared__ __align__(16) short Bs[2][256*32];   // 16 KB x2
    __shared__ float rs[64][4][2];
    __shared__ float mr[64][2];
    const int t = threadIdx.x;
    const int lane = t & 63;
    const int wave = t >> 6;
    const int wc = wave * 64;
    const int bm = blockIdx.x;
    const int Bbase = (MODE == 0) ? blockIdx.y * 256 : 0;
    f32x4 acc[4][4] = {};
    const int srow = lane >> 2;
    const int sk   = (lane & 3) * 8;
    const int fr = lane & 15;
    const int fk = (lane >> 4) * 8;
    auto stage = [&](int s, int k0) {
        {
            const int rb = wave*16;   // A: 64 rows, 1 gload/wave
            gload16(A + (size_t)(bm*64 + rb + srow)*Kk + k0 + sk, &As[s][rb*32]);
        }
        #pragma unroll
        for (int i = 0; i < 4; ++i) { // B: 256 rows, 4 gloads/wave
            const int rb = wave*16 + i*64;
            gload16(BT + (size_t)(Bbase + rb + srow)*Kk + k0 + sk, &Bs[s][rb*32]);
        }
    };
    stage(0, 0);
    __syncthreads();
    int cur = 0;
    for (int k0 = 0; k0 < Kk; k0 += 32) {
        if (k0 + 32 < Kk) stage(cur ^ 1, k0 + 32);
        bf16x8 af[4], bfr[4];
        #pragma unroll
        for (int i2 = 0; i2 < 4; ++i2)
            af[i2] = *(const bf16x8*)&As[cur][(i2*16 + fr)*32 + fk];
        #pragma unroll
        for (int n2 = 0; n2 < 4; ++n2)
            bfr[n2] = *(const bf16x8*)&Bs[cur][(wc + n2*16 + fr)*32 + fk];
        #pragma unroll
        for (int i2 = 0; i2 < 4; ++i2)
            #pragma unroll
            for (int n2 = 0; n2 < 4; ++n2)
                acc[i2][n2] = __builtin_amdgcn_mfma_f32_16x16x32_bf16(
                        af[i2], bfr[n2], acc[i2][n2], 0, 0, 0);
        __syncthreads();
        cur ^= 1;
    }
    const int fq4 = (lane >> 4) * 4;
    if constexpr (MODE == 0) {
        const int chunk = (blockIdx.y*4 + (wc >> 6)) * 64;
        #pragma unroll
        for (int i2 = 0; i2 < 4; ++i2) {
            #pragma unroll
            for (int r2 = 0; r2 < 4; ++r2) {
                const int row = bm*64 + i2*16 + fq4 + r2;
                float v[4];
                #pragma unroll
                for (int n2 = 0; n2 < 4; ++n2)
                    v[n2] = gelu_f(acc[i2][n2][r2]
                                   + bias[blockIdx.y*256 + wc + n2*16 + fr]);
                short4 s4;
                s4.x = bf16s(v[0]); s4.y = bf16s(v[1]);
                s4.z = bf16s(v[2]); s4.w = bf16s(v[3]);
                *(short4*)&outb[(size_t)row*1024 + chunk + fr*4] = s4;
            }
        }
        return;
    }
    // LN modes (1, 2)
    float ps[4][4] = {}, pq[4][4] = {};
    #pragma unroll
    for (int i2 = 0; i2 < 4; ++i2) {
        #pragma unroll
        for (int n2 = 0; n2 < 4; ++n2) {
            const int c = wc + n2*16 + fr;
            const float bv = bias[c];
            #pragma unroll
            for (int r2 = 0; r2 < 4; ++r2) {
                const int row = i2*16 + fq4 + r2;
                const size_t grow = (size_t)bm*64 + row;
                float rv;
                if constexpr (MODE == 1) {
                    const int bb = (int)(grow >> 9), nn = (int)(grow & 511);
                    rv = resf[((size_t)nn*B_ + bb)*256 + c];
                } else {
                    rv = resf[grow*256 + c];
                }
                float v = acc[i2][n2][r2] + bv + rv;
                acc[i2][n2][r2] = v;
                ps[i2][r2] += v;
                pq[i2][r2] += v*v;
            }
        }
    }
    #pragma unroll
    for (int i2 = 0; i2 < 4; ++i2)
        #pragma unroll
        for (int r2 = 0; r2 < 4; ++r2)
            #pragma unroll
            for (int o = 1; o < 16; o <<= 1) {
                ps[i2][r2] += __shfl_xor(ps[i2][r2], o);
                pq[i2][r2] += __shfl_xor(pq[i2][r2], o);
            }
    if ((lane & 15) == 0) {
        #pragma unroll
        for (int i2 = 0; i2 < 4; ++i2)
            #pragma unroll
            for (int r2 = 0; r2 < 4; ++r2) {
                const int row = i2*16 + fq4 + r2;
                rs[row][wave][0] = ps[i2][r2];
                rs[row][wave][1] = pq[i2][r2];
            }
    }
    __syncthreads();
    if (t < 64) {
        float S = 0.f, Q = 0.f;
        #pragma unroll
        for (int w = 0; w < 4; ++w) { S += rs[t][w][0]; Q += rs[t][w][1]; }
        const float mean = S * (1.f/D_);
        mr[t][0] = mean;
        mr[t][1] = rsqrtf(Q * (1.f/D_) - mean*mean + 1e-5f);
    }
    __syncthreads();
    #pragma unroll
    for (int i2 = 0; i2 < 4; ++i2) {
        #pragma unroll
        for (int n2 = 0; n2 < 4; ++n2) {
            const int c = wc + n2*16 + fr;
            const float gv = g[c], bv2 = bt[c];
            #pragma unroll
            for (int r2 = 0; r2 < 4; ++r2) {
                const int row = i2*16 + fq4 + r2;
                const size_t grow = (size_t)bm*64 + row;
                const float o = (acc[i2][n2][r2] - mr[row][0])*mr[row][1]*gv + bv2;
                if constexpr (MODE == 1) {
                    out[grow*256 + c] = o;
                    outb[grow*256 + c] = bf16s(o);
                } else {
                    const int bb = (int)(grow >> 9), nn = (int)(grow & 511);
                    out[((size_t)nn*B_ + bb)*D_ + c] = o;
                }
            }
        }
    }
}

// -- fp8 edge GEMM2 (packed+swizzled operands) + bias + bf16 res + LN --------
// 2-deep prefetch + counted vmcnt (T4). Residual e2b is slot-swizzled (bslot).
__global__ __launch_bounds__(512, 4) void gemm_ln2f8(
        const unsigned char* __restrict__ A, const unsigned char* __restrict__ BT,
        const float* __restrict__ bias, const short* __restrict__ resb,
        const float* __restrict__ g, const float* __restrict__ bt,
        float* __restrict__ out)
{
    __shared__ __align__(16) unsigned char As[2][128*64];   // 8 KB x2
    __shared__ __align__(16) unsigned char Bs[2][256*64];   // 16 KB x2
    __shared__ float rs[128][4][2];
    __shared__ float mr[128][2];
    const int t = threadIdx.x;
    const int lane = t & 63;
    const int wave = t >> 6;
    const int wrg = (wave >> 2) * 64;
    const int wc  = (wave & 3) * 64;
    const int bm = blockIdx.x;
    f32x4 acc[4][4] = {};
    const int srow = lane >> 2;        // 16 rows per wave-gload (64B rows)
    const int skb  = (lane & 3) * 16;  // byte offset within row
    const int fr = lane & 15;
    const int q16 = (lane >> 4);       // k-group / 16B-slot index
    auto stage = [&](int s, int k0) {
        {
            const int rb = wave*16;    // A: 128 rows, 1 gload/wave
            gload16(A + (size_t)(bm*128 + rb + srow)*1024 + k0 + skb, &As[s][rb*64]);
        }
        #pragma unroll
        for (int i = 0; i < 2; ++i) {  // B: 256 rows, 2 gloads/wave
            const int rb = wave*16 + i*128;
            gload16(BT + (size_t)(rb + srow)*1024 + k0 + skb, &Bs[s][rb*64]);
        }
    };
    stage(0, 0);
    stage(1, 64);
    asm volatile("s_waitcnt vmcnt(3)" ::: "memory");
    __builtin_amdgcn_sched_barrier(0);
    __builtin_amdgcn_s_barrier();
    #pragma unroll
    for (int tt = 0; tt < 16; ++tt) {                  // 1024 / 64 = 16 chunks
        const int cur = tt & 1;
        long a8[2][4], b8[2][4];
        #pragma unroll
        for (int i2 = 0; i2 < 4; ++i2) {
            const int ar = wrg + i2*16 + fr;
            const i64x2 av = *(const i64x2*)&As[cur][ar*64 + ((q16 ^ (ar & 3)) << 4)];
            a8[0][i2] = av[0]; a8[1][i2] = av[1];
        }
        #pragma unroll
        for (int n2 = 0; n2 < 4; ++n2) {
            const int br = wc + n2*16 + fr;
            const i64x2 bv = *(const i64x2*)&Bs[cur][br*64 + ((q16 ^ (br & 3)) << 4)];
            b8[0][n2] = bv[0]; b8[1][n2] = bv[1];
        }
        asm volatile("s_waitcnt lgkmcnt(0)" ::: "memory");
        __builtin_amdgcn_sched_barrier(0);
        __builtin_amdgcn_s_barrier();                  // all waves done reading cur
        if (tt + 2 < 16) stage(cur, (tt + 2) * 64);
        #pragma unroll
        for (int s = 0; s < 2; ++s)
            #pragma unroll
            for (int i2 = 0; i2 < 4; ++i2)
                #pragma unroll
                for (int n2 = 0; n2 < 4; ++n2)
                    acc[i2][n2] = __builtin_amdgcn_mfma_f32_16x16x32_fp8_fp8(
                            a8[s][i2], b8[s][n2], acc[i2][n2], 0, 0, 0);
        if (tt + 2 < 16) { asm volatile("s_waitcnt vmcnt(3)" ::: "memory"); }
        else             { asm volatile("s_waitcnt vmcnt(0)" ::: "memory"); }
        __builtin_amdgcn_sched_barrier(0);
        __builtin_amdgcn_s_barrier();
    }
    const int fq4 = (lane >> 4) * 4;
    float ps[4][4] = {}, pq[4][4] = {};
    #pragma unroll
    for (int i2 = 0; i2 < 4; ++i2) {
        #pragma unroll
        for (int n2 = 0; n2 < 4; ++n2) {
            const int c = wc + n2*16 + fr;
            const float bv = bias[c];
            #pragma unroll
            for (int r2 = 0; r2 < 4; ++r2) {
                const int row = wrg + i2*16 + fq4 + r2;
                const size_t grow = (size_t)bm*128 + row;
                const int cs = bslot(c, (int)(grow & 3));
                float v = acc[i2][n2][r2]*(1.f/1024.f) + bv + b2f(resb[grow*256 + cs]);
                acc[i2][n2][r2] = v;
                ps[i2][r2] += v;
                pq[i2][r2] += v*v;
            }
        }
    }
    #pragma unroll
    for (int i2 = 0; i2 < 4; ++i2)
        #pragma unroll
        for (int r2 = 0; r2 < 4; ++r2)
            #pragma unroll
            for (int o = 1; o < 16; o <<= 1) {
                ps[i2][r2] += __shfl_xor(ps[i2][r2], o);
                pq[i2][r2] += __shfl_xor(pq[i2][r2], o);
            }
    if ((lane & 15) == 0) {
        #pragma unroll
        for (int i2 = 0; i2 < 4; ++i2)
            #pragma unroll
            for (int r2 = 0; r2 < 4; ++r2) {
                const int row = wrg + i2*16 + fq4 + r2;
                rs[row][wave & 3][0] = ps[i2][r2];
                rs[row][wave & 3][1] = pq[i2][r2];
            }
    }
    __syncthreads();
    if (t < 128) {
        float S = 0.f, Q = 0.f;
        #pragma unroll
        for (int w = 0; w < 4; ++w) { S += rs[t][w][0]; Q += rs[t][w][1]; }
        const float mean = S * (1.f/D_);
        mr[t][0] = mean;
        mr[t][1] = rsqrtf(Q * (1.f/D_) - mean*mean + 1e-5f);
    }
    __syncthreads();
    #pragma unroll
    for (int i2 = 0; i2 < 4; ++i2) {
        #pragma unroll
        for (int n2 = 0; n2 < 4; ++n2) {
            const int c = wc + n2*16 + fr;
            const float gv = g[c], bv2 = bt[c];
            #pragma unroll
            for (int r2 = 0; r2 < 4; ++r2) {
                const int row = wrg + i2*16 + fq4 + r2;
                const size_t grow = (size_t)bm*128 + row;
                out[grow*256 + c] = (acc[i2][n2][r2] - mr[row][0])*mr[row][1]*gv + bv2;
            }
        }
    }
}

// ---------------- fused flash attention: QK^T+bias -> exp -> PV -------------
__global__ __launch_bounds__(256) void attn_fused(const short* __restrict__ qkb,
        const short* __restrict__ vtb, const float* __restrict__ biasb,
        float* __restrict__ rowsum, short* __restrict__ actx)
{
    __shared__ __align__(16) short Qs[128*32];
    __shared__ __align__(16) short Ks[128*32];
    __shared__ __align__(16) short Vs[32*128];     // [dh][j], source-pre-swizzled
    __shared__ __align__(16) short Ps[128*128];    // XOR-swizzled bf16 P tile
    const int it = blockIdx.x, bh = blockIdx.y;
    const int b = bh >> 3, h = bh & 7;
    const int t = threadIdx.x;
    const int lane = t & 63;
    const int wave = t >> 6;
    const int wr0 = wave * 32;
    const int srow = lane >> 2;        // staging: 16 rows x 64B
    const int sk   = (lane & 3) * 8;
    const int srow8 = lane >> 4;       // staging: 4 rows x 256B
    const int ck16  = lane & 15;       // 16B chunk index within 128-col row
    const int fr = lane & 15;
    const int fk = (lane >> 4) * 8;
    const int fq4 = (lane >> 4) * 4;
    const int I0 = it * 128;
    #pragma unroll
    for (int i = 0; i < 2; ++i) {
        const int rb = wave*16 + i*64;
        gload16(qkb + (size_t)(b*N_ + I0 + rb + srow)*512 + h*HD_ + sk, &Qs[rb*32]);
    }
    float rsum[2][4] = {};
    f32x4 apv[2][2] = {};
    const float LOG2E = 1.4426950408889634f;
    for (int jt = 0; jt < 4; ++jt) {
        const int J0 = jt * 128;
        __syncthreads();
        #pragma unroll
        for (int i = 0; i < 2; ++i) {
            const int rb = wave*16 + i*64;
            gload16(qkb + (size_t)(b*N_ + J0 + rb + srow)*512 + 256 + h*HD_ + sk, &Ks[rb*32]);
        }
        #pragma unroll
        for (int i = 0; i < 2; ++i) {
            const int db = wave*8 + i*4;
            const int dh = db + srow8;
            gload16(vtb + ((size_t)bh*HD_ + dh)*512 + J0 + ((ck16 ^ (dh & 7)) * 8),
                    &Vs[db*128]);
        }
        __syncthreads();
        bf16x8 aq[2], kf8[8];
        #pragma unroll
        for (int i2 = 0; i2 < 2; ++i2)
            aq[i2] = *(const bf16x8*)&Qs[(wr0 + i2*16 + fr)*32 + fk];
        #pragma unroll
        for (int n2 = 0; n2 < 8; ++n2)
            kf8[n2] = *(const bf16x8*)&Ks[(n2*16 + fr)*32 + fk];
        #pragma unroll
        for (int i2 = 0; i2 < 2; ++i2) {
            #pragma unroll
            for (int n2 = 0; n2 < 8; ++n2) {
                f32x4 z = {0.f, 0.f, 0.f, 0.f};
                f32x4 s = __builtin_amdgcn_mfma_f32_16x16x32_bf16(aq[i2], kf8[n2], z, 0, 0, 0);
                const int jg = J0 + n2*16 + fr;
                #pragma unroll
                for (int r2 = 0; r2 < 4; ++r2) {
                    const int rloc = wr0 + i2*16 + fq4 + r2;
                    const float l = s[r2] + biasb[((size_t)b*N_ + I0 + rloc)*N_ + jg];
                    const float p = exp2f(fminf(l, 80.f) * LOG2E);
                    rsum[i2][r2] += p;
                    int idx = rloc*128 + n2*16 + fr;
                    idx ^= (rloc & 7) << 3;
                    Ps[idx] = bf16s(p);
                }
            }
        }
        __syncthreads();
        #pragma unroll
        for (int ks = 0; ks < 4; ++ks) {
            bf16x8 ap[2], bv[2];
            #pragma unroll
            for (int i2 = 0; i2 < 2; ++i2) {
                const int r = wr0 + i2*16 + fr;
                int idx = r*128 + ks*32 + fk;
                idx ^= (r & 7) << 3;
                ap[i2] = *(const bf16x8*)&Ps[idx];
            }
            #pragma unroll
            for (int n2 = 0; n2 < 2; ++n2) {
                const int dh = n2*16 + fr;
                const int q = lane >> 4;
                const int slot = (ks*4 + q) ^ (dh & 7);
                bv[n2] = *(const bf16x8*)&Vs[dh*128 + slot*8];
            }
            #pragma unroll
            for (int i2 = 0; i2 < 2; ++i2)
                #pragma unroll
                for (int n2 = 0; n2 < 2; ++n2)
                    apv[i2][n2] = __builtin_amdgcn_mfma_f32_16x16x32_bf16(
                            ap[i2], bv[n2], apv[i2][n2], 0, 0, 0);
        }
    }
    #pragma unroll
    for (int i2 = 0; i2 < 2; ++i2)
        #pragma unroll
        for (int r2 = 0; r2 < 4; ++r2)
            #pragma unroll
            for (int o = 1; o < 16; o <<= 1)
                rsum[i2][r2] += __shfl_xor(rsum[i2][r2], o);
    #pragma unroll
    for (int i2 = 0; i2 < 2; ++i2) {
        #pragma unroll
        for (int r2 = 0; r2 < 4; ++r2) {
            const int row = wr0 + i2*16 + fq4 + r2;
            if (fr == 0)
                rowsum[(size_t)bh*N_ + I0 + row] = rsum[i2][r2];
            const float inv = 1.f / rsum[i2][r2];
            #pragma unroll
            for (int n2 = 0; n2 < 2; ++n2)
                actx[((size_t)b*N_ + I0 + row)*D_ + h*HD_ + n2*16 + fr]
                    = bf16s(apv[i2][n2][r2] * inv);
        }
    }
}

// ---------------- LN helper (wave per row of 256) ---------------------------
__device__ inline void ln_core(float v[4], int lane, const float* __restrict__ g,
        const float* __restrict__ bt, float out[4])
{
    float s  = v[0] + v[1] + v[2] + v[3];
    float sq = v[0]*v[0] + v[1]*v[1] + v[2]*v[2] + v[3]*v[3];
    for (int o = 1; o < 64; o <<= 1) { s += __shfl_xor(s, o); sq += __shfl_xor(sq, o); }
    float mean = s * (1.f/D_);
    float rstd = rsqrtf(sq * (1.f/D_) - mean*mean + 1e-5f);
    const float4 gv = *(const float4*)(g  + lane*4);
    const float4 bv = *(const float4*)(bt + lane*4);
    out[0] = (v[0]-mean)*rstd*gv.x + bv.x;
    out[1] = (v[1]-mean)*rstd*gv.y + bv.y;
    out[2] = (v[2]-mean)*rstd*gv.z + bv.z;
    out[3] = (v[3]-mean)*rstd*gv.w + bv.w;
}

// e2 = LN(e + w*gathered), w recomputed from q,k,bias,rowsum; writes e2b with
// slot swizzle (bslot) so the edge GEMM1's LDS fragment reads are conflict-lite.
__global__ __launch_bounds__(256) void edge_update(const float* __restrict__ e,
        const float* __restrict__ x, const int* __restrict__ ei,
        const short* __restrict__ qkb, const float* __restrict__ biasb,
        const float* __restrict__ rowsum, const float* __restrict__ g,
        const float* __restrict__ bt, short* __restrict__ e2b)
{
    long row = (long)blockIdx.x*4 + (threadIdx.x >> 6);   // b*N*K + i*K + k
    int lane = threadIdx.x & 63;
    long bi = row >> 4;          // / K_
    long b = bi / N_; int i = (int)(bi % N_);
    int ej = ei[row];
    const short4 q4 = *(const short4*)(qkb + ((size_t)b*N_ + ej)*512 + lane*4);
    const short4 k4 = *(const short4*)(qkb + ((size_t)b*N_ + i)*512 + 256 + lane*4);
    float dot = b2f(q4.x)*b2f(k4.x) + b2f(q4.y)*b2f(k4.y)
              + b2f(q4.z)*b2f(k4.z) + b2f(q4.w)*b2f(k4.w);
    dot += __shfl_xor(dot, 1); dot += __shfl_xor(dot, 2); dot += __shfl_xor(dot, 4);
    const int h = lane >> 3;
    const float l = dot + biasb[((size_t)b*N_ + ej)*N_ + i];
    float p = exp2f(fminf(l, 80.f) * 1.4426950408889634f)
            / rowsum[((size_t)b*H_ + h)*N_ + ej];
    p += __shfl_xor(p, 8); p += __shfl_xor(p, 16); p += __shfl_xor(p, 32);
    const float w = p * (1.f/H_);
    const float4 ev = *(const float4*)(e + row*D_ + lane*4);
    const float4 xv = *(const float4*)(x + ((size_t)ej*B_ + b)*D_ + lane*4);
    float v[4] = {ev.x + w*xv.x, ev.y + w*xv.y, ev.z + w*xv.z, ev.w + w*xv.w};
    float o[4];
    ln_core(v, lane, g, bt, o);
    short4 s4; s4.x = bf16s(o[0]); s4.y = bf16s(o[1]); s4.z = bf16s(o[2]); s4.w = bf16s(o[3]);
    // slot-swizzled store: lane*4 shorts -> chunk(32)=lane>>3, slot=(lane>>1)&3,
    // within-slot offset=(lane&1)*4; slot ^= row&3. short4 stays intact (8B).
    const int idx = ((lane >> 3) << 5)
                  | (((((lane >> 1) & 3)) ^ ((int)row & 3)) << 3)
                  | ((lane & 1) << 2);
    *(short4*)(e2b + row*D_ + idx) = s4;
}

// ============================================================================
extern "C" void kernel_launch(void* const* d_in, const int* in_sizes, int n_in,
                              void* d_out, int out_size, void* d_ws, size_t ws_size,
                              hipStream_t stream)
{
    (void)in_sizes; (void)n_in; (void)out_size; (void)ws_size;
    const float* x    = (const float*)d_in[0];
    const float* e    = (const float*)d_in[1];
    const int*   ei   = (const int*)d_in[2];
    const float* Wq   = (const float*)d_in[3];
    const float* bq   = (const float*)d_in[4];
    const float* Wk   = (const float*)d_in[5];
    const float* bk   = (const float*)d_in[6];
    const float* Wv   = (const float*)d_in[7];
    const float* bv   = (const float*)d_in[8];
    const float* Wo   = (const float*)d_in[9];
    const float* bo   = (const float*)d_in[10];
    const float* nW1  = (const float*)d_in[11];
    const float* nb1  = (const float*)d_in[12];
    const float* nW2  = (const float*)d_in[13];
    const float* nb2  = (const float*)d_in[14];
    const float* eW1  = (const float*)d_in[15];
    const float* eb1  = (const float*)d_in[16];
    const float* eW2  = (const float*)d_in[17];
    const float* eb2  = (const float*)d_in[18];
    const float* na_g = (const float*)d_in[19];
    const float* na_b = (const float*)d_in[20];
    const float* ea_g = (const float*)d_in[21];
    const float* ea_b = (const float*)d_in[22];
    const float* nf_g = (const float*)d_in[23];
    const float* nf_b = (const float*)d_in[24];
    const float* ef_g = (const float*)d_in[25];
    const float* ef_b = (const float*)d_in[26];

    float* out1 = (float*)d_out;                       // (N,B,D)
    float* e2f  = out1 + (size_t)N_*B_*D_;             // (B,N,K,D) final

    // ---- workspace: fixed region + overlay (pre-MLP buffers alias ehid8) ---
    char* wp = (char*)d_ws;
    auto alloc = [&](size_t bytes) -> char* {
        char* p = wp; wp += (bytes + 255) & ~(size_t)255; return p;
    };
    // fixed (live across phases)
    short* WqkvT  = (short*)alloc((size_t)768*D_*2);
    float* bqkv   = (float*)alloc(768*4);
    short* WoT    = (short*)alloc((size_t)D_*D_*2);
    short* nW1T   = (short*)alloc((size_t)F_*D_*2);
    short* nW2T   = (short*)alloc((size_t)D_*F_*2);
    short* eW1T   = (short*)alloc((size_t)F_*D_*2);
    unsigned char* eW2T8 = (unsigned char*)alloc((size_t)D_*F_);
    float* rowsum = (float*)alloc((size_t)B_*H_*N_*4);
    short* e2b    = (short*)alloc((size_t)R_*D_*2);
    // overlay: phase-A buffers (dead before edge MLP) alias ehid8
    char* ov = wp;
    auto allocA = [&](size_t bytes) -> char* {
        char* p = ov; ov += (bytes + 255) & ~(size_t)255; return p;
    };
    short* xtb    = (short*)allocA((size_t)M_*D_*2);
    float* means  = (float*)allocA((size_t)R_*4);
    float* biasb  = (float*)allocA((size_t)B_*N_*N_*4);
    short* qkb    = (short*)allocA((size_t)M_*512*2);
    short* vtb    = (short*)allocA((size_t)B_*H_*HD_*N_*2);
    short* actx   = (short*)allocA((size_t)M_*D_*2);
    float* xn     = (float*)allocA((size_t)M_*D_*4);
    short* xnb    = (short*)allocA((size_t)M_*D_*2);
    short* nhid   = (short*)allocA((size_t)M_*F_*2);
    unsigned char* ehid8 = (unsigned char*)wp;  // (R_, F_) fp8 = 67 MB, aliases phase-A

    // ---- weight prep (1 launch) + bias vector ----
    transposeAll<<<dim3(32, 32, 8), 256, 0, stream>>>(Wq, Wk, Wv, Wo,
            nW1, nW2, eW1, eW2, WqkvT, WoT, nW1T, nW2T, eW1T, eW2T8);
    build_bqkv<<<3, 256, 0, stream>>>(bq, bk, bv, bqkv);
    conv_x<<<M_, 256, 0, stream>>>(x, xtb);

    // ---- attn bias ----
    edge_means<<<R_/4, 256, 0, stream>>>(e, means);
    bias_build<<<M_/16, 256, 0, stream>>>(ei, means, biasb);

    // ---- QKV (fused, q-scale folded into Wq/bq) ----
    gemm_qkv<<<dim3(M_/128, 768/128), 256, 0, stream>>>(
            xtb, WqkvT, bqkv, qkb, vtb, D_);

    // ---- attention (fused flash-style) ----
    attn_fused<<<dim3(N_/128, B_*H_), 256, 0, stream>>>(qkb, vtb, biasb, rowsum, actx);

    // ---- node path: 64-row tiles -> grids 64 / (64,4) / 64 ----
    gemm64<1><<<M_/64, 256, 0, stream>>>(
            actx, WoT, bo, x, na_g, na_b, xn, xnb, D_);
    gemm64<0><<<dim3(M_/64, F_/256), 256, 0, stream>>>(
            xnb, nW1T, nb1, nullptr, nullptr, nullptr, nullptr, nhid, D_);
    gemm64<2><<<M_/64, 256, 0, stream>>>(
            nhid, nW2T, nb2, xn, nf_g, nf_b, out1, nullptr, F_);

    // ---- edge path: slot-swizzled e2b/eW1T, fp8 hidden, T4 counted-vmcnt --
    edge_update<<<R_/4, 256, 0, stream>>>(e, x, ei, qkb, biasb, rowsum,
            ea_g, ea_b, e2b);
    gemm_gelu_f8<<<dim3(R_/128, F_/256), 512, 0, stream>>>(
            e2b, eW1T, eb1, ehid8, D_);
    gemm_ln2f8<<<R_/128, 512, 0, stream>>>(
            ehid8, eW2T8, eb2, e2b, ef_g, ef_b, e2f);
}

// Round 18
// 306.315 us; speedup vs baseline: 1.0153x; 1.0153x over previous
//
#include <hip/hip_runtime.h>
#include <hip/hip_bf16.h>
#include <hip/hip_fp8.h>
#include <math.h>

#define B_ 8
#define N_ 512
#define K_ 16
#define D_ 256
#define F_ 1024
#define H_ 8
#define HD_ 32
#define M_ (B_*N_)      // 4096 rows (b,n)
#define R_ (B_*N_*K_)   // 65536 edge rows

typedef __bf16 bf16x8 __attribute__((ext_vector_type(8)));
typedef float  f32x4  __attribute__((ext_vector_type(4)));
typedef long   i64x2  __attribute__((ext_vector_type(2)));

__device__ inline short bf16s(float f) {
    __hip_bfloat16 h = __float2bfloat16(f);
    return *reinterpret_cast<short*>(&h);
}
__device__ inline float b2f(short s) {
    union { float f; unsigned u; } v; v.u = ((unsigned)(unsigned short)s) << 16; return v.f;
}
__device__ inline unsigned char f8e4m3(float f) {
    union { __hip_fp8_e4m3 h; unsigned char c; } u;
    u.h = __hip_fp8_e4m3(f);
    return u.c;
}
// exact GELU via Abramowitz-Stegun 7.1.26 erf (|eps| <= 1.5e-7): cheap VALU
__device__ __forceinline__ float gelu_f(float x) {
    const float z = fabsf(x) * 0.70710678118654752f;
    const float t = __builtin_amdgcn_rcpf(1.f + 0.3275911f*z);
    const float p = t*(0.254829592f + t*(-0.284496736f + t*(1.421413741f
                  + t*(-1.453152027f + t*1.061405429f))));
    float er = 1.f - p*__expf(-z*z);
    er = (x >= 0.f) ? er : -er;
    return 0.5f*x*(1.f + er);
}
// packed+swizzled fp8 position within a 64B k-chunk: slot q=(w&31)>>3 holds the
// two 8B k-groups {8q.., 32+8q..}; slot XOR'd by row&3. w = k&63.
__device__ __forceinline__ int f8pos(int w, int row) {
    return ((((w >> 3) & 3) ^ (row & 3)) << 4) | ((w >> 5) << 3) | (w & 7);
}
// hidden-dim relabeling (exact; applied to BOTH hid tensors and W2 rows):
// within each 64-chunk, w -> (w&15)*4 + ((w>>4)&3)  (16x4 transpose)
__device__ __forceinline__ int hperm(int k) {
    return (k & ~63) | ((k & 15) << 2) | ((k >> 4) & 3);
}

// async global->LDS, 16B per lane; lds base must be wave-uniform (dest = base + lane*16)
__device__ __forceinline__ void gload16(const void* g, void* l) {
    __builtin_amdgcn_global_load_lds(
        (const __attribute__((address_space(1))) unsigned int*)g,
        (__attribute__((address_space(3))) unsigned int*)l, 16, 0, 0);
}

// ---------------- all weight transposes in one launch (grid.z selects) ------
// z==5 (nW2): rows stored at hperm(k). z==7 (eW2): fp8 e4m3 x64, packed+swizzled
// at k'=hperm(k) (must match gemm_gelu's permuted hidden layout).
__global__ __launch_bounds__(256) void transposeAll(
        const float* __restrict__ Wq, const float* __restrict__ Wk,
        const float* __restrict__ Wv, const float* __restrict__ Wo,
        const float* __restrict__ nW1, const float* __restrict__ nW2,
        const float* __restrict__ eW1, const float* __restrict__ eW2,
        short* __restrict__ WqkvT, short* __restrict__ WoT,
        short* __restrict__ nW1T, short* __restrict__ nW2T,
        short* __restrict__ eW1T, unsigned char* __restrict__ eW2T8)
{
    const float* W; short* WT = nullptr; int Kk, Nn; float sc = 1.f;
    switch (blockIdx.z) {
        case 0: W=Wq;  WT=WqkvT;          Kk=256;  Nn=256;  sc=0.17677669529663687f; break;
        case 1: W=Wk;  WT=WqkvT+256*256;  Kk=256;  Nn=256;  break;
        case 2: W=Wv;  WT=WqkvT+512*256;  Kk=256;  Nn=256;  break;
        case 3: W=Wo;  WT=WoT;            Kk=256;  Nn=256;  break;
        case 4: W=nW1; WT=nW1T;           Kk=256;  Nn=1024; break;
        case 5: W=nW2; WT=nW2T;           Kk=1024; Nn=256;  break;
        case 6: W=eW1; WT=eW1T;           Kk=256;  Nn=1024; break;
        default:W=eW2;                    Kk=1024; Nn=256;  break;
    }
    const int bx = blockIdx.x, by = blockIdx.y;
    if (bx >= Nn/32 || by >= Kk/32) return;
    __shared__ float tile[32][33];
    int tx = threadIdx.x & 31, ty = threadIdx.x >> 5;   // 32x8
    #pragma unroll
    for (int j = 0; j < 4; ++j) {
        int k = by*32 + ty + j*8;
        tile[ty + j*8][tx] = W[(size_t)k*Nn + bx*32 + tx];
    }
    __syncthreads();
    if (blockIdx.z == 7) {
        #pragma unroll
        for (int j = 0; j < 4; ++j) {
            int n = bx*32 + ty + j*8;
            int kp = hperm(by*32 + tx);
            eW2T8[(size_t)n*1024 + (kp & ~63) + f8pos(kp & 63, n)] =
                f8e4m3(tile[tx][ty + j*8] * 64.f);
        }
    } else if (blockIdx.z == 5) {
        #pragma unroll
        for (int j = 0; j < 4; ++j) {
            int n = bx*32 + ty + j*8;
            WT[(size_t)n*1024 + hperm(by*32 + tx)] = bf16s(tile[tx][ty + j*8]);
        }
    } else {
        #pragma unroll
        for (int j = 0; j < 4; ++j) {
            int n = bx*32 + ty + j*8;
            WT[(size_t)n*Kk + by*32 + tx] = bf16s(tile[tx][ty + j*8] * sc);
        }
    }
}

__global__ __launch_bounds__(256) void build_bqkv(const float* __restrict__ bq,
        const float* __restrict__ bk, const float* __restrict__ bv,
        float* __restrict__ bqkv)
{
    int t = blockIdx.x*256 + threadIdx.x;
    if (t >= 768) return;
    float v = (t < 256) ? bq[t]*0.17677669529663687f
            : (t < 512) ? bk[t-256] : bv[t-512];
    bqkv[t] = v;
}

// ---------------- x (N,B,D) f32 -> xtb (B*N, D) bf16 ------------------------
__global__ __launch_bounds__(256) void conv_x(const float* __restrict__ x,
        short* __restrict__ xtb)
{
    int row = blockIdx.x;         // b*N+n
    int d = threadIdx.x;
    int b = row >> 9, n = row & 511;
    xtb[(size_t)row*D_ + d] = bf16s(x[((size_t)n*B_ + b)*D_ + d]);
}

// ---------------- means[b,i,k] = mean_d e ----------------------------------
__global__ __launch_bounds__(256) void edge_means(const float* __restrict__ e,
        float* __restrict__ means)
{
    long row = (long)blockIdx.x*4 + (threadIdx.x >> 6);
    int lane = threadIdx.x & 63;
    float4 v = ((const float4*)(e + row*D_))[lane];
    float s = v.x + v.y + v.z + v.w;
    for (int o = 1; o < 64; o <<= 1) s += __shfl_xor(s, o);
    if (lane == 0) means[row] = s * (1.f/D_);
}

// zero 16 rows + serial per-row scatter (numpy last-wins) in one kernel
__global__ __launch_bounds__(256) void bias_build(const int* __restrict__ ei,
        const float* __restrict__ means, float* __restrict__ biasb)
{
    const int r0 = blockIdx.x * 16;       // 16 (b,i) rows per block
    float4* bp4 = (float4*)(biasb + (size_t)r0*N_);
    #pragma unroll
    for (int i = threadIdx.x; i < 16*N_/4; i += 256)
        bp4[i] = make_float4(0.f, 0.f, 0.f, 0.f);
    __syncthreads();
    if (threadIdx.x < 16) {
        const int idx = r0 + threadIdx.x;
        const int* ep = ei + (size_t)idx*K_;
        const float* mp = means + (size_t)idx*K_;
        float* bp = biasb + (size_t)idx*N_;
        for (int k = 0; k < K_; ++k) bp[ep[k]] = mp[k];
    }
}

// ---------------- 128x128 bf16 MFMA GEMM: QKV split output ------------------
__global__ __launch_bounds__(256) void gemm_qkv(
        const short* __restrict__ A, const short* __restrict__ BT,
        const float* __restrict__ bias, short* __restrict__ Cb,
        short* __restrict__ vtb, int Kk)
{
    __shared__ __align__(16) short As[128*32];
    __shared__ __align__(16) short Bs[128*32];
    const int t = threadIdx.x;
    const int lane = t & 63;
    const int wave = t >> 6;
    const int wr = (wave >> 1) * 64;
    const int wc = (wave & 1) * 64;
    const int bm = blockIdx.x, bn = blockIdx.y;
    f32x4 acc[4][4] = {};
    const int srow = lane >> 2;       // staging row within 16-row group
    const int sk   = (lane & 3) * 8;  // staging k offset (8 bf16 = 16B)
    const int fr = lane & 15;
    const int fk = (lane >> 4) * 8;
    for (int k0 = 0; k0 < Kk; k0 += 32) {
        __syncthreads();
        #pragma unroll
        for (int i = 0; i < 2; ++i) {
            const int rb = wave*16 + i*64;
            gload16(A  + (size_t)(bm*128 + rb + srow)*Kk + k0 + sk, &As[rb*32]);
            gload16(BT + (size_t)(bn*128 + rb + srow)*Kk + k0 + sk, &Bs[rb*32]);
        }
        __syncthreads();
        bf16x8 af[4], bfr[4];
        #pragma unroll
        for (int i2 = 0; i2 < 4; ++i2)
            af[i2] = *(const bf16x8*)&As[(wr + i2*16 + fr)*32 + fk];
        #pragma unroll
        for (int n2 = 0; n2 < 4; ++n2)
            bfr[n2] = *(const bf16x8*)&Bs[(wc + n2*16 + fr)*32 + fk];
        #pragma unroll
        for (int i2 = 0; i2 < 4; ++i2)
            #pragma unroll
            for (int n2 = 0; n2 < 4; ++n2)
                acc[i2][n2] = __builtin_amdgcn_mfma_f32_16x16x32_bf16(
                        af[i2], bfr[n2], acc[i2][n2], 0, 0, 0);
    }
    const int fq4 = (lane >> 4) * 4;
    #pragma unroll
    for (int i2 = 0; i2 < 4; ++i2) {
        #pragma unroll
        for (int n2 = 0; n2 < 4; ++n2) {
            const int col = bn*128 + wc + n2*16 + fr;
            const float bv = bias[col];
            const int rowb = bm*128 + wr + i2*16 + fq4;
            if (col < 512) {
                #pragma unroll
                for (int r2 = 0; r2 < 4; ++r2)
                    Cb[(size_t)(rowb + r2)*512 + col] = bf16s(acc[i2][n2][r2] + bv);
            } else {
                const int b = rowb >> 9, n = rowb & 511;
                const int dv = col - 512, h = dv >> 5, dh = dv & 31;
                short4 s4;
                s4.x = bf16s(acc[i2][n2][0] + bv);
                s4.y = bf16s(acc[i2][n2][1] + bv);
                s4.z = bf16s(acc[i2][n2][2] + bv);
                s4.w = bf16s(acc[i2][n2][3] + bv);
                *(short4*)&vtb[((size_t)((b*H_ + h)*HD_ + dh))*512 + n] = s4;
            }
        }
    }
}

// -- 128x256 8-wave GEMM + GELU -> packed fp8 (edge W1) ----------------------
// 2-deep prefetch + counted vmcnt (T4): raw s_barrier, no full drains in loop.
// 3 gloads/wave per stage -> vmcnt(3) == previous tile landed.
__global__ __launch_bounds__(512, 4) void gemm_gelu_f8(
        const short* __restrict__ A, const short* __restrict__ BT,
        const float* __restrict__ bias, unsigned char* __restrict__ C8, int Kk)
{
    __shared__ __align__(16) short As[2][128*32];
    __shared__ __align__(16) short Bs[2][256*32];
    const int t = threadIdx.x;
    const int lane = t & 63;
    const int wave = t >> 6;
    const int wrg = (wave >> 2) * 64;     // row group 0/64
    const int wc  = (wave & 3) * 64;      // col group 0..192
    const int bm = blockIdx.x, bn = blockIdx.y;
    f32x4 acc[4][4] = {};
    const int srow = lane >> 2;
    const int sk   = (lane & 3) * 8;
    const int fr = lane & 15;
    const int fk = (lane >> 4) * 8;
    auto stage = [&](int s, int k0) {
        {
            const int rb = wave*16;   // A: 128 rows, 1 gload/wave
            gload16(A + (size_t)(bm*128 + rb + srow)*Kk + k0 + sk, &As[s][rb*32]);
        }
        #pragma unroll
        for (int i = 0; i < 2; ++i) {  // B: 256 rows, 2 gloads/wave
            const int rb = wave*16 + i*128;
            gload16(BT + (size_t)(bn*256 + rb + srow)*Kk + k0 + sk, &Bs[s][rb*32]);
        }
    };
    stage(0, 0);
    stage(1, 32);
    asm volatile("s_waitcnt vmcnt(3)" ::: "memory");   // own tile-0 loads landed
    __builtin_amdgcn_sched_barrier(0);
    __builtin_amdgcn_s_barrier();                      // all waves' tile-0 landed
    #pragma unroll
    for (int tt = 0; tt < 8; ++tt) {                   // Kk == 256, 8 tiles
        const int cur = tt & 1;
        bf16x8 af[4], bfr[4];
        #pragma unroll
        for (int i2 = 0; i2 < 4; ++i2)
            af[i2] = *(const bf16x8*)&As[cur][(wrg + i2*16 + fr)*32 + fk];
        #pragma unroll
        for (int n2 = 0; n2 < 4; ++n2)
            bfr[n2] = *(const bf16x8*)&Bs[cur][(wc + n2*16 + fr)*32 + fk];
        asm volatile("s_waitcnt lgkmcnt(0)" ::: "memory");  // own frags in regs
        __builtin_amdgcn_sched_barrier(0);
        __builtin_amdgcn_s_barrier();                  // all waves done reading cur
        if (tt + 2 < 8) stage(cur, (tt + 2) * 32);     // overwrite freed buffer
        #pragma unroll
        for (int i2 = 0; i2 < 4; ++i2)
            #pragma unroll
            for (int n2 = 0; n2 < 4; ++n2)
                acc[i2][n2] = __builtin_amdgcn_mfma_f32_16x16x32_bf16(
                        af[i2], bfr[n2], acc[i2][n2], 0, 0, 0);
        if (tt + 2 < 8) { asm volatile("s_waitcnt vmcnt(3)" ::: "memory"); }
        else            { asm volatile("s_waitcnt vmcnt(0)" ::: "memory"); }
        __builtin_amdgcn_sched_barrier(0);
        __builtin_amdgcn_s_barrier();                  // next tile ready for all
    }
    const int fq4 = (lane >> 4) * 4;
    const int chunk = (bn*4 + (wc >> 6)) * 64;   // this wave's 64-wide k'-chunk
    #pragma unroll
    for (int i2 = 0; i2 < 4; ++i2) {
        #pragma unroll
        for (int r2 = 0; r2 < 4; ++r2) {
            const int row = bm*128 + wrg + i2*16 + fq4 + r2;
            float v[4];
            #pragma unroll
            for (int n2 = 0; n2 < 4; ++n2)
                v[n2] = gelu_f(acc[i2][n2][r2] + bias[bn*256 + wc + n2*16 + fr]);
            int word = __builtin_amdgcn_cvt_pk_fp8_f32(v[0]*16.f, v[1]*16.f, 0, false);
            word = __builtin_amdgcn_cvt_pk_fp8_f32(v[2]*16.f, v[3]*16.f, word, true);
            *(unsigned int*)(C8 + (size_t)row*1024 + chunk + f8pos(fr*4, row))
                = (unsigned int)word;
        }
    }
}

// -- 64x256 4-wave GEMM, 2-phase prefetch dbuf (node path / Wo: grid >= 64) --
// MODE 0: + GELU -> bf16 hperm-packed out (node W1; grid (M/64, Nn/256))
// MODE 1: + bias + x-residual (N,B,D) + LN -> f32 out + bf16 outb (Wo)
// MODE 2: + bias + f32 residual + LN -> f32 out transposed (N,B,D) (node W2)
template<int MODE>
__global__ __launch_bounds__(256, 3) void gemm64(
        const short* __restrict__ A, const short* __restrict__ BT,
        const float* __restrict__ bias, const float* __restrict__ resf,
        const float* __restrict__ g, const float* __restrict__ bt,
        float* __restrict__ out, short* __restrict__ outb, int Kk)
{
    __shared__ __align__(16) short As[2][64*32];    // 4 KB x2
    __shared__ __align__(16) short Bs[2][256*32];   // 16 KB x2
    __shared__ float rs[64][4][2];
    __shared__ float mr[64][2];
    const int t = threadIdx.x;
    const int lane = t & 63;
    const int wave = t >> 6;
    const int wc = wave * 64;
    const int bm = blockIdx.x;
    const int Bbase = (MODE == 0) ? blockIdx.y * 256 : 0;
    f32x4 acc[4][4] = {};
    const int srow = lane >> 2;
    const int sk   = (lane & 3) * 8;
    const int fr = lane & 15;
    const int fk = (lane >> 4) * 8;
    auto stage = [&](int s, int k0) {
        {
            const int rb = wave*16;   // A: 64 rows, 1 gload/wave
            gload16(A + (size_t)(bm*64 + rb + srow)*Kk + k0 + sk, &As[s][rb*32]);
        }
        #pragma unroll
        for (int i = 0; i < 4; ++i) { // B: 256 rows, 4 gloads/wave
            const int rb = wave*16 + i*64;
            gload16(BT + (size_t)(Bbase + rb + srow)*Kk + k0 + sk, &Bs[s][rb*32]);
        }
    };
    stage(0, 0);
    __syncthreads();
    int cur = 0;
    for (int k0 = 0; k0 < Kk; k0 += 32) {
        if (k0 + 32 < Kk) stage(cur ^ 1, k0 + 32);
        bf16x8 af[4], bfr[4];
        #pragma unroll
        for (int i2 = 0; i2 < 4; ++i2)
            af[i2] = *(const bf16x8*)&As[cur][(i2*16 + fr)*32 + fk];
        #pragma unroll
        for (int n2 = 0; n2 < 4; ++n2)
            bfr[n2] = *(const bf16x8*)&Bs[cur][(wc + n2*16 + fr)*32 + fk];
        #pragma unroll
        for (int i2 = 0; i2 < 4; ++i2)
            #pragma unroll
            for (int n2 = 0; n2 < 4; ++n2)
                acc[i2][n2] = __builtin_amdgcn_mfma_f32_16x16x32_bf16(
                        af[i2], bfr[n2], acc[i2][n2], 0, 0, 0);
        __syncthreads();
        cur ^= 1;
    }
    const int fq4 = (lane >> 4) * 4;
    if constexpr (MODE == 0) {
        const int chunk = (blockIdx.y*4 + (wc >> 6)) * 64;
        #pragma unroll
        for (int i2 = 0; i2 < 4; ++i2) {
            #pragma unroll
            for (int r2 = 0; r2 < 4; ++r2) {
                const int row = bm*64 + i2*16 + fq4 + r2;
                float v[4];
                #pragma unroll
                for (int n2 = 0; n2 < 4; ++n2)
                    v[n2] = gelu_f(acc[i2][n2][r2]
                                   + bias[blockIdx.y*256 + wc + n2*16 + fr]);
                short4 s4;
                s4.x = bf16s(v[0]); s4.y = bf16s(v[1]);
                s4.z = bf16s(v[2]); s4.w = bf16s(v[3]);
                *(short4*)&outb[(size_t)row*1024 + chunk + fr*4] = s4;
            }
        }
        return;
    }
    // LN modes (1, 2)
    float ps[4][4] = {}, pq[4][4] = {};
    #pragma unroll
    for (int i2 = 0; i2 < 4; ++i2) {
        #pragma unroll
        for (int n2 = 0; n2 < 4; ++n2) {
            const int c = wc + n2*16 + fr;
            const float bv = bias[c];
            #pragma unroll
            for (int r2 = 0; r2 < 4; ++r2) {
                const int row = i2*16 + fq4 + r2;
                const size_t grow = (size_t)bm*64 + row;
                float rv;
                if constexpr (MODE == 1) {
                    const int bb = (int)(grow >> 9), nn = (int)(grow & 511);
                    rv = resf[((size_t)nn*B_ + bb)*256 + c];
                } else {
                    rv = resf[grow*256 + c];
                }
                float v = acc[i2][n2][r2] + bv + rv;
                acc[i2][n2][r2] = v;
                ps[i2][r2] += v;
                pq[i2][r2] += v*v;
            }
        }
    }
    #pragma unroll
    for (int i2 = 0; i2 < 4; ++i2)
        #pragma unroll
        for (int r2 = 0; r2 < 4; ++r2)
            #pragma unroll
            for (int o = 1; o < 16; o <<= 1) {
                ps[i2][r2] += __shfl_xor(ps[i2][r2], o);
                pq[i2][r2] += __shfl_xor(pq[i2][r2], o);
            }
    if ((lane & 15) == 0) {
        #pragma unroll
        for (int i2 = 0; i2 < 4; ++i2)
            #pragma unroll
            for (int r2 = 0; r2 < 4; ++r2) {
                const int row = i2*16 + fq4 + r2;
                rs[row][wave][0] = ps[i2][r2];
                rs[row][wave][1] = pq[i2][r2];
            }
    }
    __syncthreads();
    if (t < 64) {
        float S = 0.f, Q = 0.f;
        #pragma unroll
        for (int w = 0; w < 4; ++w) { S += rs[t][w][0]; Q += rs[t][w][1]; }
        const float mean = S * (1.f/D_);
        mr[t][0] = mean;
        mr[t][1] = rsqrtf(Q * (1.f/D_) - mean*mean + 1e-5f);
    }
    __syncthreads();
    #pragma unroll
    for (int i2 = 0; i2 < 4; ++i2) {
        #pragma unroll
        for (int n2 = 0; n2 < 4; ++n2) {
            const int c = wc + n2*16 + fr;
            const float gv = g[c], bv2 = bt[c];
            #pragma unroll
            for (int r2 = 0; r2 < 4; ++r2) {
                const int row = i2*16 + fq4 + r2;
                const size_t grow = (size_t)bm*64 + row;
                const float o = (acc[i2][n2][r2] - mr[row][0])*mr[row][1]*gv + bv2;
                if constexpr (MODE == 1) {
                    out[grow*256 + c] = o;
                    outb[grow*256 + c] = bf16s(o);
                } else {
                    const int bb = (int)(grow >> 9), nn = (int)(grow & 511);
                    out[((size_t)nn*B_ + bb)*D_ + c] = o;
                }
            }
        }
    }
}

// -- fp8 edge GEMM2 (packed+swizzled operands) + bias + bf16 res + LN --------
// 2-deep prefetch + counted vmcnt (T4). 3 gloads/wave per stage -> vmcnt(3).
__global__ __launch_bounds__(512, 4) void gemm_ln2f8(
        const unsigned char* __restrict__ A, const unsigned char* __restrict__ BT,
        const float* __restrict__ bias, const short* __restrict__ resb,
        const float* __restrict__ g, const float* __restrict__ bt,
        float* __restrict__ out)
{
    __shared__ __align__(16) unsigned char As[2][128*64];   // 8 KB x2
    __shared__ __align__(16) unsigned char Bs[2][256*64];   // 16 KB x2
    __shared__ float rs[128][4][2];
    __shared__ float mr[128][2];
    const int t = threadIdx.x;
    const int lane = t & 63;
    const int wave = t >> 6;
    const int wrg = (wave >> 2) * 64;
    const int wc  = (wave & 3) * 64;
    const int bm = blockIdx.x;
    f32x4 acc[4][4] = {};
    const int srow = lane >> 2;        // 16 rows per wave-gload (64B rows)
    const int skb  = (lane & 3) * 16;  // byte offset within row
    const int fr = lane & 15;
    const int q16 = (lane >> 4);       // k-group / 16B-slot index
    auto stage = [&](int s, int k0) {
        {
            const int rb = wave*16;    // A: 128 rows, 1 gload/wave
            gload16(A + (size_t)(bm*128 + rb + srow)*1024 + k0 + skb, &As[s][rb*64]);
        }
        #pragma unroll
        for (int i = 0; i < 2; ++i) {  // B: 256 rows, 2 gloads/wave
            const int rb = wave*16 + i*128;
            gload16(BT + (size_t)(rb + srow)*1024 + k0 + skb, &Bs[s][rb*64]);
        }
    };
    stage(0, 0);
    stage(1, 64);
    asm volatile("s_waitcnt vmcnt(3)" ::: "memory");
    __builtin_amdgcn_sched_barrier(0);
    __builtin_amdgcn_s_barrier();
    #pragma unroll
    for (int tt = 0; tt < 16; ++tt) {                  // 1024 / 64 = 16 chunks
        const int cur = tt & 1;
        long a8[2][4], b8[2][4];
        #pragma unroll
        for (int i2 = 0; i2 < 4; ++i2) {
            const int ar = wrg + i2*16 + fr;
            const i64x2 av = *(const i64x2*)&As[cur][ar*64 + ((q16 ^ (ar & 3)) << 4)];
            a8[0][i2] = av[0]; a8[1][i2] = av[1];
        }
        #pragma unroll
        for (int n2 = 0; n2 < 4; ++n2) {
            const int br = wc + n2*16 + fr;
            const i64x2 bv = *(const i64x2*)&Bs[cur][br*64 + ((q16 ^ (br & 3)) << 4)];
            b8[0][n2] = bv[0]; b8[1][n2] = bv[1];
        }
        asm volatile("s_waitcnt lgkmcnt(0)" ::: "memory");
        __builtin_amdgcn_sched_barrier(0);
        __builtin_amdgcn_s_barrier();                  // all waves done reading cur
        if (tt + 2 < 16) stage(cur, (tt + 2) * 64);
        #pragma unroll
        for (int s = 0; s < 2; ++s)
            #pragma unroll
            for (int i2 = 0; i2 < 4; ++i2)
                #pragma unroll
                for (int n2 = 0; n2 < 4; ++n2)
                    acc[i2][n2] = __builtin_amdgcn_mfma_f32_16x16x32_fp8_fp8(
                            a8[s][i2], b8[s][n2], acc[i2][n2], 0, 0, 0);
        if (tt + 2 < 16) { asm volatile("s_waitcnt vmcnt(3)" ::: "memory"); }
        else             { asm volatile("s_waitcnt vmcnt(0)" ::: "memory"); }
        __builtin_amdgcn_sched_barrier(0);
        __builtin_amdgcn_s_barrier();
    }
    const int fq4 = (lane >> 4) * 4;
    float ps[4][4] = {}, pq[4][4] = {};
    #pragma unroll
    for (int i2 = 0; i2 < 4; ++i2) {
        #pragma unroll
        for (int n2 = 0; n2 < 4; ++n2) {
            const int c = wc + n2*16 + fr;
            const float bv = bias[c];
            #pragma unroll
            for (int r2 = 0; r2 < 4; ++r2) {
                const int row = wrg + i2*16 + fq4 + r2;
                const size_t grow = (size_t)bm*128 + row;
                float v = acc[i2][n2][r2]*(1.f/1024.f) + bv + b2f(resb[grow*256 + c]);
                acc[i2][n2][r2] = v;
                ps[i2][r2] += v;
                pq[i2][r2] += v*v;
            }
        }
    }
    #pragma unroll
    for (int i2 = 0; i2 < 4; ++i2)
        #pragma unroll
        for (int r2 = 0; r2 < 4; ++r2)
            #pragma unroll
            for (int o = 1; o < 16; o <<= 1) {
                ps[i2][r2] += __shfl_xor(ps[i2][r2], o);
                pq[i2][r2] += __shfl_xor(pq[i2][r2], o);
            }
    if ((lane & 15) == 0) {
        #pragma unroll
        for (int i2 = 0; i2 < 4; ++i2)
            #pragma unroll
            for (int r2 = 0; r2 < 4; ++r2) {
                const int row = wrg + i2*16 + fq4 + r2;
                rs[row][wave & 3][0] = ps[i2][r2];
                rs[row][wave & 3][1] = pq[i2][r2];
            }
    }
    __syncthreads();
    if (t < 128) {
        float S = 0.f, Q = 0.f;
        #pragma unroll
        for (int w = 0; w < 4; ++w) { S += rs[t][w][0]; Q += rs[t][w][1]; }
        const float mean = S * (1.f/D_);
        mr[t][0] = mean;
        mr[t][1] = rsqrtf(Q * (1.f/D_) - mean*mean + 1e-5f);
    }
    __syncthreads();
    #pragma unroll
    for (int i2 = 0; i2 < 4; ++i2) {
        #pragma unroll
        for (int n2 = 0; n2 < 4; ++n2) {
            const int c = wc + n2*16 + fr;
            const float gv = g[c], bv2 = bt[c];
            #pragma unroll
            for (int r2 = 0; r2 < 4; ++r2) {
                const int row = wrg + i2*16 + fq4 + r2;
                const size_t grow = (size_t)bm*128 + row;
                out[grow*256 + c] = (acc[i2][n2][r2] - mr[row][0])*mr[row][1]*gv + bv2;
            }
        }
    }
}

// ---------------- fused flash attention: QK^T+bias -> exp -> PV -------------
__global__ __launch_bounds__(256) void attn_fused(const short* __restrict__ qkb,
        const short* __restrict__ vtb, const float* __restrict__ biasb,
        float* __restrict__ rowsum, short* __restrict__ actx)
{
    __shared__ __align__(16) short Qs[128*32];
    __shared__ __align__(16) short Ks[128*32];
    __shared__ __align__(16) short Vs[32*128];     // [dh][j], source-pre-swizzled
    __shared__ __align__(16) short Ps[128*128];    // XOR-swizzled bf16 P tile
    const int it = blockIdx.x, bh = blockIdx.y;
    const int b = bh >> 3, h = bh & 7;
    const int t = threadIdx.x;
    const int lane = t & 63;
    const int wave = t >> 6;
    const int wr0 = wave * 32;
    const int srow = lane >> 2;        // staging: 16 rows x 64B
    const int sk   = (lane & 3) * 8;
    const int srow8 = lane >> 4;       // staging: 4 rows x 256B
    const int ck16  = lane & 15;       // 16B chunk index within 128-col row
    const int fr = lane & 15;
    const int fk = (lane >> 4) * 8;
    const int fq4 = (lane >> 4) * 4;
    const int I0 = it * 128;
    #pragma unroll
    for (int i = 0; i < 2; ++i) {
        const int rb = wave*16 + i*64;
        gload16(qkb + (size_t)(b*N_ + I0 + rb + srow)*512 + h*HD_ + sk, &Qs[rb*32]);
    }
    float rsum[2][4] = {};
    f32x4 apv[2][2] = {};
    const float LOG2E = 1.4426950408889634f;
    for (int jt = 0; jt < 4; ++jt) {
        const int J0 = jt * 128;
        __syncthreads();
        #pragma unroll
        for (int i = 0; i < 2; ++i) {
            const int rb = wave*16 + i*64;
            gload16(qkb + (size_t)(b*N_ + J0 + rb + srow)*512 + 256 + h*HD_ + sk, &Ks[rb*32]);
        }
        #pragma unroll
        for (int i = 0; i < 2; ++i) {
            const int db = wave*8 + i*4;
            const int dh = db + srow8;
            gload16(vtb + ((size_t)bh*HD_ + dh)*512 + J0 + ((ck16 ^ (dh & 7)) * 8),
                    &Vs[db*128]);
        }
        __syncthreads();
        bf16x8 aq[2], kf8[8];
        #pragma unroll
        for (int i2 = 0; i2 < 2; ++i2)
            aq[i2] = *(const bf16x8*)&Qs[(wr0 + i2*16 + fr)*32 + fk];
        #pragma unroll
        for (int n2 = 0; n2 < 8; ++n2)
            kf8[n2] = *(const bf16x8*)&Ks[(n2*16 + fr)*32 + fk];
        #pragma unroll
        for (int i2 = 0; i2 < 2; ++i2) {
            #pragma unroll
            for (int n2 = 0; n2 < 8; ++n2) {
                f32x4 z = {0.f, 0.f, 0.f, 0.f};
                f32x4 s = __builtin_amdgcn_mfma_f32_16x16x32_bf16(aq[i2], kf8[n2], z, 0, 0, 0);
                const int jg = J0 + n2*16 + fr;
                #pragma unroll
                for (int r2 = 0; r2 < 4; ++r2) {
                    const int rloc = wr0 + i2*16 + fq4 + r2;
                    const float l = s[r2] + biasb[((size_t)b*N_ + I0 + rloc)*N_ + jg];
                    const float p = exp2f(fminf(l, 80.f) * LOG2E);
                    rsum[i2][r2] += p;
                    int idx = rloc*128 + n2*16 + fr;
                    idx ^= (rloc & 7) << 3;
                    Ps[idx] = bf16s(p);
                }
            }
        }
        __syncthreads();
        #pragma unroll
        for (int ks = 0; ks < 4; ++ks) {
            bf16x8 ap[2], bv[2];
            #pragma unroll
            for (int i2 = 0; i2 < 2; ++i2) {
                const int r = wr0 + i2*16 + fr;
                int idx = r*128 + ks*32 + fk;
                idx ^= (r & 7) << 3;
                ap[i2] = *(const bf16x8*)&Ps[idx];
            }
            #pragma unroll
            for (int n2 = 0; n2 < 2; ++n2) {
                const int dh = n2*16 + fr;
                const int q = lane >> 4;
                const int slot = (ks*4 + q) ^ (dh & 7);
                bv[n2] = *(const bf16x8*)&Vs[dh*128 + slot*8];
            }
            #pragma unroll
            for (int i2 = 0; i2 < 2; ++i2)
                #pragma unroll
                for (int n2 = 0; n2 < 2; ++n2)
                    apv[i2][n2] = __builtin_amdgcn_mfma_f32_16x16x32_bf16(
                            ap[i2], bv[n2], apv[i2][n2], 0, 0, 0);
        }
    }
    #pragma unroll
    for (int i2 = 0; i2 < 2; ++i2)
        #pragma unroll
        for (int r2 = 0; r2 < 4; ++r2)
            #pragma unroll
            for (int o = 1; o < 16; o <<= 1)
                rsum[i2][r2] += __shfl_xor(rsum[i2][r2], o);
    #pragma unroll
    for (int i2 = 0; i2 < 2; ++i2) {
        #pragma unroll
        for (int r2 = 0; r2 < 4; ++r2) {
            const int row = wr0 + i2*16 + fq4 + r2;
            if (fr == 0)
                rowsum[(size_t)bh*N_ + I0 + row] = rsum[i2][r2];
            const float inv = 1.f / rsum[i2][r2];
            #pragma unroll
            for (int n2 = 0; n2 < 2; ++n2)
                actx[((size_t)b*N_ + I0 + row)*D_ + h*HD_ + n2*16 + fr]
                    = bf16s(apv[i2][n2][r2] * inv);
        }
    }
}

// ---------------- LN helper (wave per row of 256) ---------------------------
__device__ inline void ln_core(float v[4], int lane, const float* __restrict__ g,
        const float* __restrict__ bt, float out[4])
{
    float s  = v[0] + v[1] + v[2] + v[3];
    float sq = v[0]*v[0] + v[1]*v[1] + v[2]*v[2] + v[3]*v[3];
    for (int o = 1; o < 64; o <<= 1) { s += __shfl_xor(s, o); sq += __shfl_xor(sq, o); }
    float mean = s * (1.f/D_);
    float rstd = rsqrtf(sq * (1.f/D_) - mean*mean + 1e-5f);
    const float4 gv = *(const float4*)(g  + lane*4);
    const float4 bv = *(const float4*)(bt + lane*4);
    out[0] = (v[0]-mean)*rstd*gv.x + bv.x;
    out[1] = (v[1]-mean)*rstd*gv.y + bv.y;
    out[2] = (v[2]-mean)*rstd*gv.z + bv.z;
    out[3] = (v[3]-mean)*rstd*gv.w + bv.w;
}

// e2 = LN(e + w*gathered), w recomputed from q,k,bias,rowsum; writes bf16 only
__global__ __launch_bounds__(256) void edge_update(const float* __restrict__ e,
        const float* __restrict__ x, const int* __restrict__ ei,
        const short* __restrict__ qkb, const float* __restrict__ biasb,
        const float* __restrict__ rowsum, const float* __restrict__ g,
        const float* __restrict__ bt, short* __restrict__ e2b)
{
    long row = (long)blockIdx.x*4 + (threadIdx.x >> 6);   // b*N*K + i*K + k
    int lane = threadIdx.x & 63;
    long bi = row >> 4;          // / K_
    long b = bi / N_; int i = (int)(bi % N_);
    int ej = ei[row];
    const short4 q4 = *(const short4*)(qkb + ((size_t)b*N_ + ej)*512 + lane*4);
    const short4 k4 = *(const short4*)(qkb + ((size_t)b*N_ + i)*512 + 256 + lane*4);
    float dot = b2f(q4.x)*b2f(k4.x) + b2f(q4.y)*b2f(k4.y)
              + b2f(q4.z)*b2f(k4.z) + b2f(q4.w)*b2f(k4.w);
    dot += __shfl_xor(dot, 1); dot += __shfl_xor(dot, 2); dot += __shfl_xor(dot, 4);
    const int h = lane >> 3;
    const float l = dot + biasb[((size_t)b*N_ + ej)*N_ + i];
    float p = exp2f(fminf(l, 80.f) * 1.4426950408889634f)
            / rowsum[((size_t)b*H_ + h)*N_ + ej];
    p += __shfl_xor(p, 8); p += __shfl_xor(p, 16); p += __shfl_xor(p, 32);
    const float w = p * (1.f/H_);
    const float4 ev = *(const float4*)(e + row*D_ + lane*4);
    const float4 xv = *(const float4*)(x + ((size_t)ej*B_ + b)*D_ + lane*4);
    float v[4] = {ev.x + w*xv.x, ev.y + w*xv.y, ev.z + w*xv.z, ev.w + w*xv.w};
    float o[4];
    ln_core(v, lane, g, bt, o);
    short4 s4; s4.x = bf16s(o[0]); s4.y = bf16s(o[1]); s4.z = bf16s(o[2]); s4.w = bf16s(o[3]);
    *(short4*)(e2b + row*D_ + lane*4) = s4;
}

// ============================================================================
extern "C" void kernel_launch(void* const* d_in, const int* in_sizes, int n_in,
                              void* d_out, int out_size, void* d_ws, size_t ws_size,
                              hipStream_t stream)
{
    (void)in_sizes; (void)n_in; (void)out_size; (void)ws_size;
    const float* x    = (const float*)d_in[0];
    const float* e    = (const float*)d_in[1];
    const int*   ei   = (const int*)d_in[2];
    const float* Wq   = (const float*)d_in[3];
    const float* bq   = (const float*)d_in[4];
    const float* Wk   = (const float*)d_in[5];
    const float* bk   = (const float*)d_in[6];
    const float* Wv   = (const float*)d_in[7];
    const float* bv   = (const float*)d_in[8];
    const float* Wo   = (const float*)d_in[9];
    const float* bo   = (const float*)d_in[10];
    const float* nW1  = (const float*)d_in[11];
    const float* nb1  = (const float*)d_in[12];
    const float* nW2  = (const float*)d_in[13];
    const float* nb2  = (const float*)d_in[14];
    const float* eW1  = (const float*)d_in[15];
    const float* eb1  = (const float*)d_in[16];
    const float* eW2  = (const float*)d_in[17];
    const float* eb2  = (const float*)d_in[18];
    const float* na_g = (const float*)d_in[19];
    const float* na_b = (const float*)d_in[20];
    const float* ea_g = (const float*)d_in[21];
    const float* ea_b = (const float*)d_in[22];
    const float* nf_g = (const float*)d_in[23];
    const float* nf_b = (const float*)d_in[24];
    const float* ef_g = (const float*)d_in[25];
    const float* ef_b = (const float*)d_in[26];

    float* out1 = (float*)d_out;                       // (N,B,D)
    float* e2f  = out1 + (size_t)N_*B_*D_;             // (B,N,K,D) final

    // ---- workspace: fixed region + overlay (pre-MLP buffers alias ehid8) ---
    char* wp = (char*)d_ws;
    auto alloc = [&](size_t bytes) -> char* {
        char* p = wp; wp += (bytes + 255) & ~(size_t)255; return p;
    };
    // fixed (live across phases)
    short* WqkvT  = (short*)alloc((size_t)768*D_*2);
    float* bqkv   = (float*)alloc(768*4);
    short* WoT    = (short*)alloc((size_t)D_*D_*2);
    short* nW1T   = (short*)alloc((size_t)F_*D_*2);
    short* nW2T   = (short*)alloc((size_t)D_*F_*2);
    short* eW1T   = (short*)alloc((size_t)F_*D_*2);
    unsigned char* eW2T8 = (unsigned char*)alloc((size_t)D_*F_);
    float* rowsum = (float*)alloc((size_t)B_*H_*N_*4);
    short* e2b    = (short*)alloc((size_t)R_*D_*2);
    // overlay: phase-A buffers (dead before edge MLP) alias ehid8
    char* ov = wp;
    auto allocA = [&](size_t bytes) -> char* {
        char* p = ov; ov += (bytes + 255) & ~(size_t)255; return p;
    };
    short* xtb    = (short*)allocA((size_t)M_*D_*2);
    float* means  = (float*)allocA((size_t)R_*4);
    float* biasb  = (float*)allocA((size_t)B_*N_*N_*4);
    short* qkb    = (short*)allocA((size_t)M_*512*2);
    short* vtb    = (short*)allocA((size_t)B_*H_*HD_*N_*2);
    short* actx   = (short*)allocA((size_t)M_*D_*2);
    float* xn     = (float*)allocA((size_t)M_*D_*4);
    short* xnb    = (short*)allocA((size_t)M_*D_*2);
    short* nhid   = (short*)allocA((size_t)M_*F_*2);
    unsigned char* ehid8 = (unsigned char*)wp;  // (R_, F_) fp8 = 67 MB, aliases phase-A

    // ---- weight prep (1 launch) + bias vector ----
    transposeAll<<<dim3(32, 32, 8), 256, 0, stream>>>(Wq, Wk, Wv, Wo,
            nW1, nW2, eW1, eW2, WqkvT, WoT, nW1T, nW2T, eW1T, eW2T8);
    build_bqkv<<<3, 256, 0, stream>>>(bq, bk, bv, bqkv);
    conv_x<<<M_, 256, 0, stream>>>(x, xtb);

    // ---- attn bias ----
    edge_means<<<R_/4, 256, 0, stream>>>(e, means);
    bias_build<<<M_/16, 256, 0, stream>>>(ei, means, biasb);

    // ---- QKV (fused, q-scale folded into Wq/bq) ----
    gemm_qkv<<<dim3(M_/128, 768/128), 256, 0, stream>>>(
            xtb, WqkvT, bqkv, qkb, vtb, D_);

    // ---- attention (fused flash-style) ----
    attn_fused<<<dim3(N_/128, B_*H_), 256, 0, stream>>>(qkb, vtb, biasb, rowsum, actx);

    // ---- node path: 64-row tiles -> grids 64 / (64,4) / 64 ----
    gemm64<1><<<M_/64, 256, 0, stream>>>(
            actx, WoT, bo, x, na_g, na_b, xn, xnb, D_);
    gemm64<0><<<dim3(M_/64, F_/256), 256, 0, stream>>>(
            xnb, nW1T, nb1, nullptr, nullptr, nullptr, nullptr, nhid, D_);
    gemm64<2><<<M_/64, 256, 0, stream>>>(
            nhid, nW2T, nb2, xn, nf_g, nf_b, out1, nullptr, F_);

    // ---- edge path: fp8 hidden (packed+swizzled+hperm), T4 counted-vmcnt --
    edge_update<<<R_/4, 256, 0, stream>>>(e, x, ei, qkb, biasb, rowsum,
            ea_g, ea_b, e2b);
    gemm_gelu_f8<<<dim3(R_/128, F_/256), 512, 0, stream>>>(
            e2b, eW1T, eb1, ehid8, D_);
    gemm_ln2f8<<<R_/128, 512, 0, stream>>>(
            ehid8, eW2T8, eb2, e2b, ef_g, ef_b, e2f);
}

// Round 19
// 301.481 us; speedup vs baseline: 1.0316x; 1.0160x over previous
//
#include <hip/hip_runtime.h>
#include <hip/hip_bf16.h>
#include <hip/hip_fp8.h>
#include <math.h>

#define B_ 8
#define N_ 512
#define K_ 16
#define D_ 256
#define F_ 1024
#define H_ 8
#define HD_ 32
#define M_ (B_*N_)      // 4096 rows (b,n)
#define R_ (B_*N_*K_)   // 65536 edge rows

typedef __bf16 bf16x8 __attribute__((ext_vector_type(8)));
typedef float  f32x4  __attribute__((ext_vector_type(4)));
typedef long   i64x2  __attribute__((ext_vector_type(2)));

__device__ inline short bf16s(float f) {
    __hip_bfloat16 h = __float2bfloat16(f);
    return *reinterpret_cast<short*>(&h);
}
__device__ inline float b2f(short s) {
    union { float f; unsigned u; } v; v.u = ((unsigned)(unsigned short)s) << 16; return v.f;
}
__device__ inline unsigned char f8e4m3(float f) {
    union { __hip_fp8_e4m3 h; unsigned char c; } u;
    u.h = __hip_fp8_e4m3(f);
    return u.c;
}
// exact GELU via Abramowitz-Stegun 7.1.26 erf (|eps| <= 1.5e-7): cheap VALU
__device__ __forceinline__ float gelu_f(float x) {
    const float z = fabsf(x) * 0.70710678118654752f;
    const float t = __builtin_amdgcn_rcpf(1.f + 0.3275911f*z);
    const float p = t*(0.254829592f + t*(-0.284496736f + t*(1.421413741f
                  + t*(-1.453152027f + t*1.061405429f))));
    float er = 1.f - p*__expf(-z*z);
    er = (x >= 0.f) ? er : -er;
    return 0.5f*x*(1.f + er);
}
// packed+swizzled fp8 position within a 64B k-chunk: slot q=(w&31)>>3 holds the
// two 8B k-groups {8q.., 32+8q..}; slot XOR'd by row&3. w = k&63.
__device__ __forceinline__ int f8pos(int w, int row) {
    return ((((w >> 3) & 3) ^ (row & 3)) << 4) | ((w >> 5) << 3) | (w & 7);
}
// hidden-dim relabeling (exact; applied to BOTH hid tensors and W2 rows):
// within each 64-chunk, w -> (w&15)*4 + ((w>>4)&3)  (16x4 transpose)
__device__ __forceinline__ int hperm(int k) {
    return (k & ~63) | ((k & 15) << 2) | ((k >> 4) & 3);
}

// async global->LDS, 16B per lane; lds base must be wave-uniform (dest = base + lane*16)
__device__ __forceinline__ void gload16(const void* g, void* l) {
    __builtin_amdgcn_global_load_lds(
        (const __attribute__((address_space(1))) unsigned int*)g,
        (__attribute__((address_space(3))) unsigned int*)l, 16, 0, 0);
}

// ---------------- all weight transposes in one launch (grid.z selects) ------
// z==5 (nW2): rows stored at hperm(k). z==7 (eW2): fp8 e4m3 x64, packed+swizzled
// at k'=hperm(k) (must match gemm_gelu's permuted hidden layout).
__global__ __launch_bounds__(256) void transposeAll(
        const float* __restrict__ Wq, const float* __restrict__ Wk,
        const float* __restrict__ Wv, const float* __restrict__ Wo,
        const float* __restrict__ nW1, const float* __restrict__ nW2,
        const float* __restrict__ eW1, const float* __restrict__ eW2,
        short* __restrict__ WqkvT, short* __restrict__ WoT,
        short* __restrict__ nW1T, short* __restrict__ nW2T,
        short* __restrict__ eW1T, unsigned char* __restrict__ eW2T8)
{
    const float* W; short* WT = nullptr; int Kk, Nn; float sc = 1.f;
    switch (blockIdx.z) {
        case 0: W=Wq;  WT=WqkvT;          Kk=256;  Nn=256;  sc=0.17677669529663687f; break;
        case 1: W=Wk;  WT=WqkvT+256*256;  Kk=256;  Nn=256;  break;
        case 2: W=Wv;  WT=WqkvT+512*256;  Kk=256;  Nn=256;  break;
        case 3: W=Wo;  WT=WoT;            Kk=256;  Nn=256;  break;
        case 4: W=nW1; WT=nW1T;           Kk=256;  Nn=1024; break;
        case 5: W=nW2; WT=nW2T;           Kk=1024; Nn=256;  break;
        case 6: W=eW1; WT=eW1T;           Kk=256;  Nn=1024; break;
        default:W=eW2;                    Kk=1024; Nn=256;  break;
    }
    const int bx = blockIdx.x, by = blockIdx.y;
    if (bx >= Nn/32 || by >= Kk/32) return;
    __shared__ float tile[32][33];
    int tx = threadIdx.x & 31, ty = threadIdx.x >> 5;   // 32x8
    #pragma unroll
    for (int j = 0; j < 4; ++j) {
        int k = by*32 + ty + j*8;
        tile[ty + j*8][tx] = W[(size_t)k*Nn + bx*32 + tx];
    }
    __syncthreads();
    if (blockIdx.z == 7) {
        #pragma unroll
        for (int j = 0; j < 4; ++j) {
            int n = bx*32 + ty + j*8;
            int kp = hperm(by*32 + tx);
            eW2T8[(size_t)n*1024 + (kp & ~63) + f8pos(kp & 63, n)] =
                f8e4m3(tile[tx][ty + j*8] * 64.f);
        }
    } else if (blockIdx.z == 5) {
        #pragma unroll
        for (int j = 0; j < 4; ++j) {
            int n = bx*32 + ty + j*8;
            WT[(size_t)n*1024 + hperm(by*32 + tx)] = bf16s(tile[tx][ty + j*8]);
        }
    } else {
        #pragma unroll
        for (int j = 0; j < 4; ++j) {
            int n = bx*32 + ty + j*8;
            WT[(size_t)n*Kk + by*32 + tx] = bf16s(tile[tx][ty + j*8] * sc);
        }
    }
}

// ---------------- fused prep: conv_x + build_bqkv + edge_means --------------
// blocks [0, M_): xtb row conversion (blocks 0-2 also fill bqkv);
// blocks [M_, M_+R_/4): edge means, 4 rows per block.
__global__ __launch_bounds__(256) void prep_fused(
        const float* __restrict__ x, short* __restrict__ xtb,
        const float* __restrict__ e, float* __restrict__ means,
        const float* __restrict__ bq, const float* __restrict__ bk,
        const float* __restrict__ bv, float* __restrict__ bqkv)
{
    const int blk = blockIdx.x;
    if (blk < M_) {
        const int row = blk;
        const int d = threadIdx.x;
        const int b = row >> 9, n = row & 511;
        xtb[(size_t)row*D_ + d] = bf16s(x[((size_t)n*B_ + b)*D_ + d]);
        if (blk < 3) {
            const int t = blk*256 + threadIdx.x;   // 0..767
            float v = (t < 256) ? bq[t]*0.17677669529663687f
                    : (t < 512) ? bk[t-256] : bv[t-512];
            bqkv[t] = v;
        }
    } else {
        const long row = (long)(blk - M_)*4 + (threadIdx.x >> 6);
        const int lane = threadIdx.x & 63;
        float4 v = ((const float4*)(e + row*D_))[lane];
        float s = v.x + v.y + v.z + v.w;
        for (int o = 1; o < 64; o <<= 1) s += __shfl_xor(s, o);
        if (lane == 0) means[row] = s * (1.f/D_);
    }
}

// zero 16 rows + serial per-row scatter (numpy last-wins) in one kernel
__global__ __launch_bounds__(256) void bias_build(const int* __restrict__ ei,
        const float* __restrict__ means, float* __restrict__ biasb)
{
    const int r0 = blockIdx.x * 16;       // 16 (b,i) rows per block
    float4* bp4 = (float4*)(biasb + (size_t)r0*N_);
    #pragma unroll
    for (int i = threadIdx.x; i < 16*N_/4; i += 256)
        bp4[i] = make_float4(0.f, 0.f, 0.f, 0.f);
    __syncthreads();
    if (threadIdx.x < 16) {
        const int idx = r0 + threadIdx.x;
        const int* ep = ei + (size_t)idx*K_;
        const float* mp = means + (size_t)idx*K_;
        float* bp = biasb + (size_t)idx*N_;
        for (int k = 0; k < K_; ++k) bp[ep[k]] = mp[k];
    }
}

// ---------------- 128x128 bf16 MFMA GEMM: QKV split output ------------------
__global__ __launch_bounds__(256) void gemm_qkv(
        const short* __restrict__ A, const short* __restrict__ BT,
        const float* __restrict__ bias, short* __restrict__ Cb,
        short* __restrict__ vtb, int Kk)
{
    __shared__ __align__(16) short As[128*32];
    __shared__ __align__(16) short Bs[128*32];
    const int t = threadIdx.x;
    const int lane = t & 63;
    const int wave = t >> 6;
    const int wr = (wave >> 1) * 64;
    const int wc = (wave & 1) * 64;
    const int bm = blockIdx.x, bn = blockIdx.y;
    f32x4 acc[4][4] = {};
    const int srow = lane >> 2;       // staging row within 16-row group
    const int sk   = (lane & 3) * 8;  // staging k offset (8 bf16 = 16B)
    const int fr = lane & 15;
    const int fk = (lane >> 4) * 8;
    for (int k0 = 0; k0 < Kk; k0 += 32) {
        __syncthreads();
        #pragma unroll
        for (int i = 0; i < 2; ++i) {
            const int rb = wave*16 + i*64;
            gload16(A  + (size_t)(bm*128 + rb + srow)*Kk + k0 + sk, &As[rb*32]);
            gload16(BT + (size_t)(bn*128 + rb + srow)*Kk + k0 + sk, &Bs[rb*32]);
        }
        __syncthreads();
        bf16x8 af[4], bfr[4];
        #pragma unroll
        for (int i2 = 0; i2 < 4; ++i2)
            af[i2] = *(const bf16x8*)&As[(wr + i2*16 + fr)*32 + fk];
        #pragma unroll
        for (int n2 = 0; n2 < 4; ++n2)
            bfr[n2] = *(const bf16x8*)&Bs[(wc + n2*16 + fr)*32 + fk];
        #pragma unroll
        for (int i2 = 0; i2 < 4; ++i2)
            #pragma unroll
            for (int n2 = 0; n2 < 4; ++n2)
                acc[i2][n2] = __builtin_amdgcn_mfma_f32_16x16x32_bf16(
                        af[i2], bfr[n2], acc[i2][n2], 0, 0, 0);
    }
    const int fq4 = (lane >> 4) * 4;
    #pragma unroll
    for (int i2 = 0; i2 < 4; ++i2) {
        #pragma unroll
        for (int n2 = 0; n2 < 4; ++n2) {
            const int col = bn*128 + wc + n2*16 + fr;
            const float bv = bias[col];
            const int rowb = bm*128 + wr + i2*16 + fq4;
            if (col < 512) {
                #pragma unroll
                for (int r2 = 0; r2 < 4; ++r2)
                    Cb[(size_t)(rowb + r2)*512 + col] = bf16s(acc[i2][n2][r2] + bv);
            } else {
                const int b = rowb >> 9, n = rowb & 511;
                const int dv = col - 512, h = dv >> 5, dh = dv & 31;
                short4 s4;
                s4.x = bf16s(acc[i2][n2][0] + bv);
                s4.y = bf16s(acc[i2][n2][1] + bv);
                s4.z = bf16s(acc[i2][n2][2] + bv);
                s4.w = bf16s(acc[i2][n2][3] + bv);
                *(short4*)&vtb[((size_t)((b*H_ + h)*HD_ + dh))*512 + n] = s4;
            }
        }
    }
}

// -- 128x256 8-wave GEMM + GELU -> packed fp8 (edge W1) ----------------------
// 2-deep prefetch + counted vmcnt (T4): raw s_barrier, no full drains in loop.
// 3 gloads/wave per stage -> vmcnt(3) == previous tile landed.
__global__ __launch_bounds__(512, 4) void gemm_gelu_f8(
        const short* __restrict__ A, const short* __restrict__ BT,
        const float* __restrict__ bias, unsigned char* __restrict__ C8, int Kk)
{
    __shared__ __align__(16) short As[2][128*32];
    __shared__ __align__(16) short Bs[2][256*32];
    const int t = threadIdx.x;
    const int lane = t & 63;
    const int wave = t >> 6;
    const int wrg = (wave >> 2) * 64;     // row group 0/64
    const int wc  = (wave & 3) * 64;      // col group 0..192
    const int bm = blockIdx.x, bn = blockIdx.y;
    f32x4 acc[4][4] = {};
    const int srow = lane >> 2;
    const int sk   = (lane & 3) * 8;
    const int fr = lane & 15;
    const int fk = (lane >> 4) * 8;
    auto stage = [&](int s, int k0) {
        {
            const int rb = wave*16;   // A: 128 rows, 1 gload/wave
            gload16(A + (size_t)(bm*128 + rb + srow)*Kk + k0 + sk, &As[s][rb*32]);
        }
        #pragma unroll
        for (int i = 0; i < 2; ++i) {  // B: 256 rows, 2 gloads/wave
            const int rb = wave*16 + i*128;
            gload16(BT + (size_t)(bn*256 + rb + srow)*Kk + k0 + sk, &Bs[s][rb*32]);
        }
    };
    stage(0, 0);
    stage(1, 32);
    asm volatile("s_waitcnt vmcnt(3)" ::: "memory");   // own tile-0 loads landed
    __builtin_amdgcn_sched_barrier(0);
    __builtin_amdgcn_s_barrier();                      // all waves' tile-0 landed
    #pragma unroll
    for (int tt = 0; tt < 8; ++tt) {                   // Kk == 256, 8 tiles
        const int cur = tt & 1;
        bf16x8 af[4], bfr[4];
        #pragma unroll
        for (int i2 = 0; i2 < 4; ++i2)
            af[i2] = *(const bf16x8*)&As[cur][(wrg + i2*16 + fr)*32 + fk];
        #pragma unroll
        for (int n2 = 0; n2 < 4; ++n2)
            bfr[n2] = *(const bf16x8*)&Bs[cur][(wc + n2*16 + fr)*32 + fk];
        asm volatile("s_waitcnt lgkmcnt(0)" ::: "memory");  // own frags in regs
        __builtin_amdgcn_sched_barrier(0);
        __builtin_amdgcn_s_barrier();                  // all waves done reading cur
        if (tt + 2 < 8) stage(cur, (tt + 2) * 32);     // overwrite freed buffer
        #pragma unroll
        for (int i2 = 0; i2 < 4; ++i2)
            #pragma unroll
            for (int n2 = 0; n2 < 4; ++n2)
                acc[i2][n2] = __builtin_amdgcn_mfma_f32_16x16x32_bf16(
                        af[i2], bfr[n2], acc[i2][n2], 0, 0, 0);
        if (tt + 2 < 8) { asm volatile("s_waitcnt vmcnt(3)" ::: "memory"); }
        else            { asm volatile("s_waitcnt vmcnt(0)" ::: "memory"); }
        __builtin_amdgcn_sched_barrier(0);
        __builtin_amdgcn_s_barrier();                  // next tile ready for all
    }
    const int fq4 = (lane >> 4) * 4;
    const int chunk = (bn*4 + (wc >> 6)) * 64;   // this wave's 64-wide k'-chunk
    #pragma unroll
    for (int i2 = 0; i2 < 4; ++i2) {
        #pragma unroll
        for (int r2 = 0; r2 < 4; ++r2) {
            const int row = bm*128 + wrg + i2*16 + fq4 + r2;
            float v[4];
            #pragma unroll
            for (int n2 = 0; n2 < 4; ++n2)
                v[n2] = gelu_f(acc[i2][n2][r2] + bias[bn*256 + wc + n2*16 + fr]);
            int word = __builtin_amdgcn_cvt_pk_fp8_f32(v[0]*16.f, v[1]*16.f, 0, false);
            word = __builtin_amdgcn_cvt_pk_fp8_f32(v[2]*16.f, v[3]*16.f, word, true);
            *(unsigned int*)(C8 + (size_t)row*1024 + chunk + f8pos(fr*4, row))
                = (unsigned int)word;
        }
    }
}

// -- 64x256 4-wave GEMM, 2-phase prefetch dbuf (node path / Wo: grid >= 64) --
// MODE 0: + GELU -> bf16 hperm-packed out (node W1; grid (M/64, Nn/256))
// MODE 1: + bias + x-residual (N,B,D) + LN -> f32 out + bf16 outb (Wo)
// MODE 2: + bias + f32 residual + LN -> f32 out transposed (N,B,D) (node W2)
template<int MODE>
__global__ __launch_bounds__(256, 3) void gemm64(
        const short* __restrict__ A, const short* __restrict__ BT,
        const float* __restrict__ bias, const float* __restrict__ resf,
        const float* __restrict__ g, const float* __restrict__ bt,
        float* __restrict__ out, short* __restrict__ outb, int Kk)
{
    __shared__ __align__(16) short As[2][64*32];    // 4 KB x2
    __shared__ __align__(16) short Bs[2][256*32];   // 16 KB x2
    __shared__ float rs[64][4][2];
    __shared__ float mr[64][2];
    const int t = threadIdx.x;
    const int lane = t & 63;
    const int wave = t >> 6;
    const int wc = wave * 64;
    const int bm = blockIdx.x;
    const int Bbase = (MODE == 0) ? blockIdx.y * 256 : 0;
    f32x4 acc[4][4] = {};
    const int srow = lane >> 2;
    const int sk   = (lane & 3) * 8;
    const int fr = lane & 15;
    const int fk = (lane >> 4) * 8;
    auto stage = [&](int s, int k0) {
        {
            const int rb = wave*16;   // A: 64 rows, 1 gload/wave
            gload16(A + (size_t)(bm*64 + rb + srow)*Kk + k0 + sk, &As[s][rb*32]);
        }
        #pragma unroll
        for (int i = 0; i < 4; ++i) { // B: 256 rows, 4 gloads/wave
            const int rb = wave*16 + i*64;
            gload16(BT + (size_t)(Bbase + rb + srow)*Kk + k0 + sk, &Bs[s][rb*32]);
        }
    };
    stage(0, 0);
    __syncthreads();
    int cur = 0;
    for (int k0 = 0; k0 < Kk; k0 += 32) {
        if (k0 + 32 < Kk) stage(cur ^ 1, k0 + 32);
        bf16x8 af[4], bfr[4];
        #pragma unroll
        for (int i2 = 0; i2 < 4; ++i2)
            af[i2] = *(const bf16x8*)&As[cur][(i2*16 + fr)*32 + fk];
        #pragma unroll
        for (int n2 = 0; n2 < 4; ++n2)
            bfr[n2] = *(const bf16x8*)&Bs[cur][(wc + n2*16 + fr)*32 + fk];
        #pragma unroll
        for (int i2 = 0; i2 < 4; ++i2)
            #pragma unroll
            for (int n2 = 0; n2 < 4; ++n2)
                acc[i2][n2] = __builtin_amdgcn_mfma_f32_16x16x32_bf16(
                        af[i2], bfr[n2], acc[i2][n2], 0, 0, 0);
        __syncthreads();
        cur ^= 1;
    }
    const int fq4 = (lane >> 4) * 4;
    if constexpr (MODE == 0) {
        const int chunk = (blockIdx.y*4 + (wc >> 6)) * 64;
        #pragma unroll
        for (int i2 = 0; i2 < 4; ++i2) {
            #pragma unroll
            for (int r2 = 0; r2 < 4; ++r2) {
                const int row = bm*64 + i2*16 + fq4 + r2;
                float v[4];
                #pragma unroll
                for (int n2 = 0; n2 < 4; ++n2)
                    v[n2] = gelu_f(acc[i2][n2][r2]
                                   + bias[blockIdx.y*256 + wc + n2*16 + fr]);
                short4 s4;
                s4.x = bf16s(v[0]); s4.y = bf16s(v[1]);
                s4.z = bf16s(v[2]); s4.w = bf16s(v[3]);
                *(short4*)&outb[(size_t)row*1024 + chunk + fr*4] = s4;
            }
        }
        return;
    }
    // LN modes (1, 2)
    float ps[4][4] = {}, pq[4][4] = {};
    #pragma unroll
    for (int i2 = 0; i2 < 4; ++i2) {
        #pragma unroll
        for (int n2 = 0; n2 < 4; ++n2) {
            const int c = wc + n2*16 + fr;
            const float bv = bias[c];
            #pragma unroll
            for (int r2 = 0; r2 < 4; ++r2) {
                const int row = i2*16 + fq4 + r2;
                const size_t grow = (size_t)bm*64 + row;
                float rv;
                if constexpr (MODE == 1) {
                    const int bb = (int)(grow >> 9), nn = (int)(grow & 511);
                    rv = resf[((size_t)nn*B_ + bb)*256 + c];
                } else {
                    rv = resf[grow*256 + c];
                }
                float v = acc[i2][n2][r2] + bv + rv;
                acc[i2][n2][r2] = v;
                ps[i2][r2] += v;
                pq[i2][r2] += v*v;
            }
        }
    }
    #pragma unroll
    for (int i2 = 0; i2 < 4; ++i2)
        #pragma unroll
        for (int r2 = 0; r2 < 4; ++r2)
            #pragma unroll
            for (int o = 1; o < 16; o <<= 1) {
                ps[i2][r2] += __shfl_xor(ps[i2][r2], o);
                pq[i2][r2] += __shfl_xor(pq[i2][r2], o);
            }
    if ((lane & 15) == 0) {
        #pragma unroll
        for (int i2 = 0; i2 < 4; ++i2)
            #pragma unroll
            for (int r2 = 0; r2 < 4; ++r2) {
                const int row = i2*16 + fq4 + r2;
                rs[row][wave][0] = ps[i2][r2];
                rs[row][wave][1] = pq[i2][r2];
            }
    }
    __syncthreads();
    if (t < 64) {
        float S = 0.f, Q = 0.f;
        #pragma unroll
        for (int w = 0; w < 4; ++w) { S += rs[t][w][0]; Q += rs[t][w][1]; }
        const float mean = S * (1.f/D_);
        mr[t][0] = mean;
        mr[t][1] = rsqrtf(Q * (1.f/D_) - mean*mean + 1e-5f);
    }
    __syncthreads();
    #pragma unroll
    for (int i2 = 0; i2 < 4; ++i2) {
        #pragma unroll
        for (int n2 = 0; n2 < 4; ++n2) {
            const int c = wc + n2*16 + fr;
            const float gv = g[c], bv2 = bt[c];
            #pragma unroll
            for (int r2 = 0; r2 < 4; ++r2) {
                const int row = i2*16 + fq4 + r2;
                const size_t grow = (size_t)bm*64 + row;
                const float o = (acc[i2][n2][r2] - mr[row][0])*mr[row][1]*gv + bv2;
                if constexpr (MODE == 1) {
                    out[grow*256 + c] = o;
                    outb[grow*256 + c] = bf16s(o);
                } else {
                    const int bb = (int)(grow >> 9), nn = (int)(grow & 511);
                    out[((size_t)nn*B_ + bb)*D_ + c] = o;
                }
            }
        }
    }
}

// -- fp8 edge GEMM2 (packed+swizzled operands) + bias + bf16 res + LN --------
// 2-deep prefetch + counted vmcnt (T4). 3 gloads/wave per stage -> vmcnt(3).
__global__ __launch_bounds__(512, 4) void gemm_ln2f8(
        const unsigned char* __restrict__ A, const unsigned char* __restrict__ BT,
        const float* __restrict__ bias, const short* __restrict__ resb,
        const float* __restrict__ g, const float* __restrict__ bt,
        float* __restrict__ out)
{
    __shared__ __align__(16) unsigned char As[2][128*64];   // 8 KB x2
    __shared__ __align__(16) unsigned char Bs[2][256*64];   // 16 KB x2
    __shared__ float rs[128][4][2];
    __shared__ float mr[128][2];
    const int t = threadIdx.x;
    const int lane = t & 63;
    const int wave = t >> 6;
    const int wrg = (wave >> 2) * 64;
    const int wc  = (wave & 3) * 64;
    const int bm = blockIdx.x;
    f32x4 acc[4][4] = {};
    const int srow = lane >> 2;        // 16 rows per wave-gload (64B rows)
    const int skb  = (lane & 3) * 16;  // byte offset within row
    const int fr = lane & 15;
    const int q16 = (lane >> 4);       // k-group / 16B-slot index
    auto stage = [&](int s, int k0) {
        {
            const int rb = wave*16;    // A: 128 rows, 1 gload/wave
            gload16(A + (size_t)(bm*128 + rb + srow)*1024 + k0 + skb, &As[s][rb*64]);
        }
        #pragma unroll
        for (int i = 0; i < 2; ++i) {  // B: 256 rows, 2 gloads/wave
            const int rb = wave*16 + i*128;
            gload16(BT + (size_t)(rb + srow)*1024 + k0 + skb, &Bs[s][rb*64]);
        }
    };
    stage(0, 0);
    stage(1, 64);
    asm volatile("s_waitcnt vmcnt(3)" ::: "memory");
    __builtin_amdgcn_sched_barrier(0);
    __builtin_amdgcn_s_barrier();
    #pragma unroll
    for (int tt = 0; tt < 16; ++tt) {                  // 1024 / 64 = 16 chunks
        const int cur = tt & 1;
        long a8[2][4], b8[2][4];
        #pragma unroll
        for (int i2 = 0; i2 < 4; ++i2) {
            const int ar = wrg + i2*16 + fr;
            const i64x2 av = *(const i64x2*)&As[cur][ar*64 + ((q16 ^ (ar & 3)) << 4)];
            a8[0][i2] = av[0]; a8[1][i2] = av[1];
        }
        #pragma unroll
        for (int n2 = 0; n2 < 4; ++n2) {
            const int br = wc + n2*16 + fr;
            const i64x2 bv = *(const i64x2*)&Bs[cur][br*64 + ((q16 ^ (br & 3)) << 4)];
            b8[0][n2] = bv[0]; b8[1][n2] = bv[1];
        }
        asm volatile("s_waitcnt lgkmcnt(0)" ::: "memory");
        __builtin_amdgcn_sched_barrier(0);
        __builtin_amdgcn_s_barrier();                  // all waves done reading cur
        if (tt + 2 < 16) stage(cur, (tt + 2) * 64);
        #pragma unroll
        for (int s = 0; s < 2; ++s)
            #pragma unroll
            for (int i2 = 0; i2 < 4; ++i2)
                #pragma unroll
                for (int n2 = 0; n2 < 4; ++n2)
                    acc[i2][n2] = __builtin_amdgcn_mfma_f32_16x16x32_fp8_fp8(
                            a8[s][i2], b8[s][n2], acc[i2][n2], 0, 0, 0);
        if (tt + 2 < 16) { asm volatile("s_waitcnt vmcnt(3)" ::: "memory"); }
        else             { asm volatile("s_waitcnt vmcnt(0)" ::: "memory"); }
        __builtin_amdgcn_sched_barrier(0);
        __builtin_amdgcn_s_barrier();
    }
    const int fq4 = (lane >> 4) * 4;
    float ps[4][4] = {}, pq[4][4] = {};
    #pragma unroll
    for (int i2 = 0; i2 < 4; ++i2) {
        #pragma unroll
        for (int n2 = 0; n2 < 4; ++n2) {
            const int c = wc + n2*16 + fr;
            const float bv = bias[c];
            #pragma unroll
            for (int r2 = 0; r2 < 4; ++r2) {
                const int row = wrg + i2*16 + fq4 + r2;
                const size_t grow = (size_t)bm*128 + row;
                float v = acc[i2][n2][r2]*(1.f/1024.f) + bv + b2f(resb[grow*256 + c]);
                acc[i2][n2][r2] = v;
                ps[i2][r2] += v;
                pq[i2][r2] += v*v;
            }
        }
    }
    #pragma unroll
    for (int i2 = 0; i2 < 4; ++i2)
        #pragma unroll
        for (int r2 = 0; r2 < 4; ++r2)
            #pragma unroll
            for (int o = 1; o < 16; o <<= 1) {
                ps[i2][r2] += __shfl_xor(ps[i2][r2], o);
                pq[i2][r2] += __shfl_xor(pq[i2][r2], o);
            }
    if ((lane & 15) == 0) {
        #pragma unroll
        for (int i2 = 0; i2 < 4; ++i2)
            #pragma unroll
            for (int r2 = 0; r2 < 4; ++r2) {
                const int row = wrg + i2*16 + fq4 + r2;
                rs[row][wave & 3][0] = ps[i2][r2];
                rs[row][wave & 3][1] = pq[i2][r2];
            }
    }
    __syncthreads();
    if (t < 128) {
        float S = 0.f, Q = 0.f;
        #pragma unroll
        for (int w = 0; w < 4; ++w) { S += rs[t][w][0]; Q += rs[t][w][1]; }
        const float mean = S * (1.f/D_);
        mr[t][0] = mean;
        mr[t][1] = rsqrtf(Q * (1.f/D_) - mean*mean + 1e-5f);
    }
    __syncthreads();
    #pragma unroll
    for (int i2 = 0; i2 < 4; ++i2) {
        #pragma unroll
        for (int n2 = 0; n2 < 4; ++n2) {
            const int c = wc + n2*16 + fr;
            const float gv = g[c], bv2 = bt[c];
            #pragma unroll
            for (int r2 = 0; r2 < 4; ++r2) {
                const int row = wrg + i2*16 + fq4 + r2;
                const size_t grow = (size_t)bm*128 + row;
                out[grow*256 + c] = (acc[i2][n2][r2] - mr[row][0])*mr[row][1]*gv + bv2;
            }
        }
    }
}

// ---------------- fused flash attention: QK^T+bias -> exp -> PV -------------
__global__ __launch_bounds__(256) void attn_fused(const short* __restrict__ qkb,
        const short* __restrict__ vtb, const float* __restrict__ biasb,
        float* __restrict__ rowsum, short* __restrict__ actx)
{
    __shared__ __align__(16) short Qs[128*32];
    __shared__ __align__(16) short Ks[128*32];
    __shared__ __align__(16) short Vs[32*128];     // [dh][j], source-pre-swizzled
    __shared__ __align__(16) short Ps[128*128];    // XOR-swizzled bf16 P tile
    const int it = blockIdx.x, bh = blockIdx.y;
    const int b = bh >> 3, h = bh & 7;
    const int t = threadIdx.x;
    const int lane = t & 63;
    const int wave = t >> 6;
    const int wr0 = wave * 32;
    const int srow = lane >> 2;        // staging: 16 rows x 64B
    const int sk   = (lane & 3) * 8;
    const int srow8 = lane >> 4;       // staging: 4 rows x 256B
    const int ck16  = lane & 15;       // 16B chunk index within 128-col row
    const int fr = lane & 15;
    const int fk = (lane >> 4) * 8;
    const int fq4 = (lane >> 4) * 4;
    const int I0 = it * 128;
    #pragma unroll
    for (int i = 0; i < 2; ++i) {
        const int rb = wave*16 + i*64;
        gload16(qkb + (size_t)(b*N_ + I0 + rb + srow)*512 + h*HD_ + sk, &Qs[rb*32]);
    }
    float rsum[2][4] = {};
    f32x4 apv[2][2] = {};
    const float LOG2E = 1.4426950408889634f;
    for (int jt = 0; jt < 4; ++jt) {
        const int J0 = jt * 128;
        __syncthreads();
        #pragma unroll
        for (int i = 0; i < 2; ++i) {
            const int rb = wave*16 + i*64;
            gload16(qkb + (size_t)(b*N_ + J0 + rb + srow)*512 + 256 + h*HD_ + sk, &Ks[rb*32]);
        }
        #pragma unroll
        for (int i = 0; i < 2; ++i) {
            const int db = wave*8 + i*4;
            const int dh = db + srow8;
            gload16(vtb + ((size_t)bh*HD_ + dh)*512 + J0 + ((ck16 ^ (dh & 7)) * 8),
                    &Vs[db*128]);
        }
        __syncthreads();
        bf16x8 aq[2], kf8[8];
        #pragma unroll
        for (int i2 = 0; i2 < 2; ++i2)
            aq[i2] = *(const bf16x8*)&Qs[(wr0 + i2*16 + fr)*32 + fk];
        #pragma unroll
        for (int n2 = 0; n2 < 8; ++n2)
            kf8[n2] = *(const bf16x8*)&Ks[(n2*16 + fr)*32 + fk];
        #pragma unroll
        for (int i2 = 0; i2 < 2; ++i2) {
            #pragma unroll
            for (int n2 = 0; n2 < 8; ++n2) {
                f32x4 z = {0.f, 0.f, 0.f, 0.f};
                f32x4 s = __builtin_amdgcn_mfma_f32_16x16x32_bf16(aq[i2], kf8[n2], z, 0, 0, 0);
                const int jg = J0 + n2*16 + fr;
                #pragma unroll
                for (int r2 = 0; r2 < 4; ++r2) {
                    const int rloc = wr0 + i2*16 + fq4 + r2;
                    const float l = s[r2] + biasb[((size_t)b*N_ + I0 + rloc)*N_ + jg];
                    const float p = exp2f(fminf(l, 80.f) * LOG2E);
                    rsum[i2][r2] += p;
                    int idx = rloc*128 + n2*16 + fr;
                    idx ^= (rloc & 7) << 3;
                    Ps[idx] = bf16s(p);
                }
            }
        }
        __syncthreads();
        #pragma unroll
        for (int ks = 0; ks < 4; ++ks) {
            bf16x8 ap[2], bv[2];
            #pragma unroll
            for (int i2 = 0; i2 < 2; ++i2) {
                const int r = wr0 + i2*16 + fr;
                int idx = r*128 + ks*32 + fk;
                idx ^= (r & 7) << 3;
                ap[i2] = *(const bf16x8*)&Ps[idx];
            }
            #pragma unroll
            for (int n2 = 0; n2 < 2; ++n2) {
                const int dh = n2*16 + fr;
                const int q = lane >> 4;
                const int slot = (ks*4 + q) ^ (dh & 7);
                bv[n2] = *(const bf16x8*)&Vs[dh*128 + slot*8];
            }
            #pragma unroll
            for (int i2 = 0; i2 < 2; ++i2)
                #pragma unroll
                for (int n2 = 0; n2 < 2; ++n2)
                    apv[i2][n2] = __builtin_amdgcn_mfma_f32_16x16x32_bf16(
                            ap[i2], bv[n2], apv[i2][n2], 0, 0, 0);
        }
    }
    #pragma unroll
    for (int i2 = 0; i2 < 2; ++i2)
        #pragma unroll
        for (int r2 = 0; r2 < 4; ++r2)
            #pragma unroll
            for (int o = 1; o < 16; o <<= 1)
                rsum[i2][r2] += __shfl_xor(rsum[i2][r2], o);
    #pragma unroll
    for (int i2 = 0; i2 < 2; ++i2) {
        #pragma unroll
        for (int r2 = 0; r2 < 4; ++r2) {
            const int row = wr0 + i2*16 + fq4 + r2;
            if (fr == 0)
                rowsum[(size_t)bh*N_ + I0 + row] = rsum[i2][r2];
            const float inv = 1.f / rsum[i2][r2];
            #pragma unroll
            for (int n2 = 0; n2 < 2; ++n2)
                actx[((size_t)b*N_ + I0 + row)*D_ + h*HD_ + n2*16 + fr]
                    = bf16s(apv[i2][n2][r2] * inv);
        }
    }
}

// ---------------- LN helper (wave per row of 256) ---------------------------
__device__ inline void ln_core(float v[4], int lane, const float* __restrict__ g,
        const float* __restrict__ bt, float out[4])
{
    float s  = v[0] + v[1] + v[2] + v[3];
    float sq = v[0]*v[0] + v[1]*v[1] + v[2]*v[2] + v[3]*v[3];
    for (int o = 1; o < 64; o <<= 1) { s += __shfl_xor(s, o); sq += __shfl_xor(sq, o); }
    float mean = s * (1.f/D_);
    float rstd = rsqrtf(sq * (1.f/D_) - mean*mean + 1e-5f);
    const float4 gv = *(const float4*)(g  + lane*4);
    const float4 bv = *(const float4*)(bt + lane*4);
    out[0] = (v[0]-mean)*rstd*gv.x + bv.x;
    out[1] = (v[1]-mean)*rstd*gv.y + bv.y;
    out[2] = (v[2]-mean)*rstd*gv.z + bv.z;
    out[3] = (v[3]-mean)*rstd*gv.w + bv.w;
}

// e2 = LN(e + w*gathered), w recomputed from q,k,bias,rowsum; writes bf16 only
__global__ __launch_bounds__(256) void edge_update(const float* __restrict__ e,
        const float* __restrict__ x, const int* __restrict__ ei,
        const short* __restrict__ qkb, const float* __restrict__ biasb,
        const float* __restrict__ rowsum, const float* __restrict__ g,
        const float* __restrict__ bt, short* __restrict__ e2b)
{
    long row = (long)blockIdx.x*4 + (threadIdx.x >> 6);   // b*N*K + i*K + k
    int lane = threadIdx.x & 63;
    long bi = row >> 4;          // / K_
    long b = bi / N_; int i = (int)(bi % N_);
    int ej = ei[row];
    const short4 q4 = *(const short4*)(qkb + ((size_t)b*N_ + ej)*512 + lane*4);
    const short4 k4 = *(const short4*)(qkb + ((size_t)b*N_ + i)*512 + 256 + lane*4);
    float dot = b2f(q4.x)*b2f(k4.x) + b2f(q4.y)*b2f(k4.y)
              + b2f(q4.z)*b2f(k4.z) + b2f(q4.w)*b2f(k4.w);
    dot += __shfl_xor(dot, 1); dot += __shfl_xor(dot, 2); dot += __shfl_xor(dot, 4);
    const int h = lane >> 3;
    const float l = dot + biasb[((size_t)b*N_ + ej)*N_ + i];
    float p = exp2f(fminf(l, 80.f) * 1.4426950408889634f)
            / rowsum[((size_t)b*H_ + h)*N_ + ej];
    p += __shfl_xor(p, 8); p += __shfl_xor(p, 16); p += __shfl_xor(p, 32);
    const float w = p * (1.f/H_);
    const float4 ev = *(const float4*)(e + row*D_ + lane*4);
    const float4 xv = *(const float4*)(x + ((size_t)ej*B_ + b)*D_ + lane*4);
    float v[4] = {ev.x + w*xv.x, ev.y + w*xv.y, ev.z + w*xv.z, ev.w + w*xv.w};
    float o[4];
    ln_core(v, lane, g, bt, o);
    short4 s4; s4.x = bf16s(o[0]); s4.y = bf16s(o[1]); s4.z = bf16s(o[2]); s4.w = bf16s(o[3]);
    *(short4*)(e2b + row*D_ + lane*4) = s4;
}

// ============================================================================
extern "C" void kernel_launch(void* const* d_in, const int* in_sizes, int n_in,
                              void* d_out, int out_size, void* d_ws, size_t ws_size,
                              hipStream_t stream)
{
    (void)in_sizes; (void)n_in; (void)out_size; (void)ws_size;
    const float* x    = (const float*)d_in[0];
    const float* e    = (const float*)d_in[1];
    const int*   ei   = (const int*)d_in[2];
    const float* Wq   = (const float*)d_in[3];
    const float* bq   = (const float*)d_in[4];
    const float* Wk   = (const float*)d_in[5];
    const float* bk   = (const float*)d_in[6];
    const float* Wv   = (const float*)d_in[7];
    const float* bv   = (const float*)d_in[8];
    const float* Wo   = (const float*)d_in[9];
    const float* bo   = (const float*)d_in[10];
    const float* nW1  = (const float*)d_in[11];
    const float* nb1  = (const float*)d_in[12];
    const float* nW2  = (const float*)d_in[13];
    const float* nb2  = (const float*)d_in[14];
    const float* eW1  = (const float*)d_in[15];
    const float* eb1  = (const float*)d_in[16];
    const float* eW2  = (const float*)d_in[17];
    const float* eb2  = (const float*)d_in[18];
    const float* na_g = (const float*)d_in[19];
    const float* na_b = (const float*)d_in[20];
    const float* ea_g = (const float*)d_in[21];
    const float* ea_b = (const float*)d_in[22];
    const float* nf_g = (const float*)d_in[23];
    const float* nf_b = (const float*)d_in[24];
    const float* ef_g = (const float*)d_in[25];
    const float* ef_b = (const float*)d_in[26];

    float* out1 = (float*)d_out;                       // (N,B,D)
    float* e2f  = out1 + (size_t)N_*B_*D_;             // (B,N,K,D) final

    // ---- workspace: fixed region + overlay (pre-MLP buffers alias ehid8) ---
    char* wp = (char*)d_ws;
    auto alloc = [&](size_t bytes) -> char* {
        char* p = wp; wp += (bytes + 255) & ~(size_t)255; return p;
    };
    // fixed (live across phases)
    short* WqkvT  = (short*)alloc((size_t)768*D_*2);
    float* bqkv   = (float*)alloc(768*4);
    short* WoT    = (short*)alloc((size_t)D_*D_*2);
    short* nW1T   = (short*)alloc((size_t)F_*D_*2);
    short* nW2T   = (short*)alloc((size_t)D_*F_*2);
    short* eW1T   = (short*)alloc((size_t)F_*D_*2);
    unsigned char* eW2T8 = (unsigned char*)alloc((size_t)D_*F_);
    float* rowsum = (float*)alloc((size_t)B_*H_*N_*4);
    short* e2b    = (short*)alloc((size_t)R_*D_*2);
    // overlay: phase-A buffers (dead before edge MLP) alias ehid8
    char* ov = wp;
    auto allocA = [&](size_t bytes) -> char* {
        char* p = ov; ov += (bytes + 255) & ~(size_t)255; return p;
    };
    short* xtb    = (short*)allocA((size_t)M_*D_*2);
    float* means  = (float*)allocA((size_t)R_*4);
    float* biasb  = (float*)allocA((size_t)B_*N_*N_*4);
    short* qkb    = (short*)allocA((size_t)M_*512*2);
    short* vtb    = (short*)allocA((size_t)B_*H_*HD_*N_*2);
    short* actx   = (short*)allocA((size_t)M_*D_*2);
    float* xn     = (float*)allocA((size_t)M_*D_*4);
    short* xnb    = (short*)allocA((size_t)M_*D_*2);
    short* nhid   = (short*)allocA((size_t)M_*F_*2);
    unsigned char* ehid8 = (unsigned char*)wp;  // (R_, F_) fp8 = 67 MB, aliases phase-A

    // ---- weight prep (1 launch) + fused conv_x/means/bqkv (1 launch) ----
    transposeAll<<<dim3(32, 32, 8), 256, 0, stream>>>(Wq, Wk, Wv, Wo,
            nW1, nW2, eW1, eW2, WqkvT, WoT, nW1T, nW2T, eW1T, eW2T8);
    prep_fused<<<M_ + R_/4, 256, 0, stream>>>(x, xtb, e, means, bq, bk, bv, bqkv);
    bias_build<<<M_/16, 256, 0, stream>>>(ei, means, biasb);

    // ---- QKV (fused, q-scale folded into Wq/bq) ----
    gemm_qkv<<<dim3(M_/128, 768/128), 256, 0, stream>>>(
            xtb, WqkvT, bqkv, qkb, vtb, D_);

    // ---- attention (fused flash-style) ----
    attn_fused<<<dim3(N_/128, B_*H_), 256, 0, stream>>>(qkb, vtb, biasb, rowsum, actx);

    // ---- node path: 64-row tiles -> grids 64 / (64,4) / 64 ----
    gemm64<1><<<M_/64, 256, 0, stream>>>(
            actx, WoT, bo, x, na_g, na_b, xn, xnb, D_);
    gemm64<0><<<dim3(M_/64, F_/256), 256, 0, stream>>>(
            xnb, nW1T, nb1, nullptr, nullptr, nullptr, nullptr, nhid, D_);
    gemm64<2><<<M_/64, 256, 0, stream>>>(
            nhid, nW2T, nb2, xn, nf_g, nf_b, out1, nullptr, F_);

    // ---- edge path: fp8 hidden (packed+swizzled+hperm), T4 counted-vmcnt --
    edge_update<<<R_/4, 256, 0, stream>>>(e, x, ei, qkb, biasb, rowsum,
            ea_g, ea_b, e2b);
    gemm_gelu_f8<<<dim3(R_/128, F_/256), 512, 0, stream>>>(
            e2b, eW1T, eb1, ehid8, D_);
    gemm_ln2f8<<<R_/128, 512, 0, stream>>>(
            ehid8, eW2T8, eb2, e2b, ef_g, ef_b, e2f);
}